// Round 1
// baseline (38545.850 us; speedup 1.0000x reference)
//
#include <hip/hip_runtime.h>
#include <hip/hip_fp16.h>

#define TT 256
#define NB 32
#define KENC 512
#define VV 10000
#define DMM 512
#define NSL 16          // slices (blocks) per batch element
#define KROWS 32        // enc k-rows per slice

typedef _Float16 f16;
typedef _Float16 f16x8 __attribute__((ext_vector_type(8)));
typedef float f32x4 __attribute__((ext_vector_type(4)));

// ---- ws layout (bytes) ----
#define CNT_OFF 0ull
#define GE_OFF 4096ull
#define GE_BYTES (8192ull*1024ull*4ull)
#define XC_OFF (GE_OFF + GE_BYTES)
#define XC_STRIDE 10240ull   // floats per b
#define XC_BYTES (32ull*XC_STRIDE*4ull)
#define PC_OFF (XC_OFF + XC_BYTES)
#define PC_BYTES (8192ull*1024ull*2ull)
#define WO_OFF (PC_OFF + PC_BYTES)
#define NPAD 10112

__device__ __forceinline__ void st_dev(float* p, float v) {
  __hip_atomic_store(p, v, __ATOMIC_RELAXED, __HIP_MEMORY_SCOPE_AGENT);
}
__device__ __forceinline__ float ld_dev(const float* p) {
  return __hip_atomic_load(p, __ATOMIC_RELAXED, __HIP_MEMORY_SCOPE_AGENT);
}
__device__ __forceinline__ float sigm(float x) { return 1.f / (1.f + __expf(-x)); }

__device__ __forceinline__ void group_barrier(int* cb, int target, int* dead_lds) {
  __syncthreads();
  if (threadIdx.x == 0) {
    __hip_atomic_fetch_add(cb, 1, __ATOMIC_RELEASE, __HIP_MEMORY_SCOPE_AGENT);
    int it = 0;
    while (__hip_atomic_load(cb, __ATOMIC_ACQUIRE, __HIP_MEMORY_SCOPE_AGENT) < target) {
      __builtin_amdgcn_s_sleep(2);
      if (++it > (1 << 20)) { *dead_lds = 1; break; }
    }
  }
  __syncthreads();
}

// ---- K1: tokens -> embedding -> g_e = e @ W_e^T + b0 (all 1024 gate rows) ----
__global__ __launch_bounds__(256) void k_embed_gates(
    const int* __restrict__ dec, const float* __restrict__ emb,
    const float* __restrict__ Wih0, const float* __restrict__ b0,
    float* __restrict__ ge)
{
  __shared__ float e_lds[8][64];
  int tid = threadIdx.x;
  int tb0 = blockIdx.x * 8;
  for (int j = tid; j < 8 * 64; j += 256) {
    int q = j >> 6, d = j & 63;
    int tb = tb0 + q;
    int t = tb >> 5, b = tb & 31;
    int tok;
    if (t == 0) tok = 1;                        // SOS
    else { tok = dec[b * 256 + (t - 1)]; if (tok == 2) tok = 0; }  // EOS->PAD
    e_lds[q][d] = emb[(size_t)tok * 64 + d];
  }
  __syncthreads();
  for (int rr = 0; rr < 4; ++rr) {
    int row = tid + rr * 256;
    float bv = b0[row];
    float acc[8];
#pragma unroll
    for (int q = 0; q < 8; ++q) acc[q] = bv;
    const float* wr = Wih0 + (size_t)row * 576;
#pragma unroll 4
    for (int d4 = 0; d4 < 16; ++d4) {
      float4 w = *(const float4*)&wr[d4 * 4];
#pragma unroll
      for (int q = 0; q < 8; ++q) {
        acc[q] += w.x * e_lds[q][d4 * 4 + 0];
        acc[q] += w.y * e_lds[q][d4 * 4 + 1];
        acc[q] += w.z * e_lds[q][d4 * 4 + 2];
        acc[q] += w.w * e_lds[q][d4 * 4 + 3];
      }
    }
#pragma unroll
    for (int q = 0; q < 8; ++q) ge[(size_t)(tb0 + q) * 1024 + row] = acc[q];
  }
}

// ---- K1b: W_out fp32 -> fp16, padded to NPAD rows ----
__global__ __launch_bounds__(256) void k_wout_f16(const float* __restrict__ W, f16* __restrict__ wo)
{
  size_t base = (size_t)blockIdx.x * 4096 + (size_t)threadIdx.x * 16;
  for (int i = 0; i < 16; ++i) {
    size_t idx = base + i;
    size_t n = idx >> 10;
    float v = (n < 10000) ? W[idx] : 0.f;
    wo[idx] = (f16)v;
  }
}

// ---- K2: sequential scan. 512 blocks = 32 b-groups x 16 slices. ----
__global__ __launch_bounds__(256) void k_seq(
    const float* __restrict__ enc, const float* __restrict__ Wih0,
    const float* __restrict__ Wih1, const float* __restrict__ b1,
    const float* __restrict__ Wproj, const float* __restrict__ bproj,
    const float* __restrict__ ge, float* __restrict__ xc, int* __restrict__ cnt,
    f16* __restrict__ pc)
{
  __shared__ f16 ench[KROWS * 512];
  __shared__ float ctx_lds[512];
  __shared__ float hbuf[256];
  __shared__ float projf[512];
  __shared__ float gred[64];
  __shared__ float sc_lds[32];
  __shared__ float el[32];
  __shared__ float mred[16], Sred[16];
  __shared__ int dead;

  int tid = threadIdx.x;
  int j = blockIdx.x;
  int b = (j & 7) * 4 + (j >> 7);     // same XCD-residue for all 16 slices of b
  int s = (j >> 3) & 15;
  float* xcb = xc + (size_t)b * XC_STRIDE;
  int* cb = cnt + b;

  // stationary enc slice -> LDS fp16, xor swizzle on d by (kk&7)<<3
  for (int i = tid; i < KROWS * 512; i += 256) {
    int kk = i >> 9, d = i & 511;
    float v = enc[((size_t)b * 512 + (s * KROWS + kk)) * 512 + d];
    ench[kk * 512 + (d ^ ((kk & 7) << 3))] = (f16)v;
  }
  for (int i = tid; i < 512; i += 256) ctx_lds[i] = 0.f;
  if (tid == 0) dead = 0;
  __syncthreads();

  int phase = 0;
  int r = tid >> 2, c4 = tid & 3;
  int rp = tid >> 3, c8 = tid & 7;

  for (int t = 0; t < TT; ++t) {
    // ---- stage A: gates = g_e + W_c @ ctx ; h0 slice ----
    if (r < 48) {
      int u = (r & 15) + s * 16;
      int row = (r < 16) ? u : (r < 32) ? 512 + u : 768 + u;
      const float* wrow = Wih0 + (size_t)row * 576 + 64 + c4 * 128;
      float acc = 0.f;
#pragma unroll 8
      for (int i2 = 0; i2 < 32; ++i2) {
        float4 w = *(const float4*)&wrow[i2 * 4];
        float4 x = *(const float4*)&ctx_lds[c4 * 128 + i2 * 4];
        acc += w.x * x.x + w.y * x.y + w.z * x.z + w.w * x.w;
      }
      acc += __shfl_xor(acc, 1, 64);
      acc += __shfl_xor(acc, 2, 64);
      if (c4 == 0) gred[r] = acc + ge[(size_t)(t * 32 + b) * 1024 + row];
    }
    __syncthreads();
    if (tid < 16) {
      float cc = sigm(gred[tid]) * tanhf(gred[16 + tid]);
      float h = sigm(gred[32 + tid]) * tanhf(cc);
      st_dev(xcb + s * 16 + tid, h);
    }
    group_barrier(cb, (++phase) * NSL, &dead);
    if (dead) break;

    // ---- stage B: h1 slice ----
    hbuf[tid] = ld_dev(xcb + tid);
    __syncthreads();
    if (r < 48) {
      int u = (r & 15) + s * 16;
      int row = (r < 16) ? u : (r < 32) ? 512 + u : 768 + u;
      const float* wrow = Wih1 + (size_t)row * 256 + c4 * 64;
      float acc = 0.f;
#pragma unroll 8
      for (int i2 = 0; i2 < 16; ++i2) {
        float4 w = *(const float4*)&wrow[i2 * 4];
        float4 x = *(const float4*)&hbuf[c4 * 64 + i2 * 4];
        acc += w.x * x.x + w.y * x.y + w.z * x.z + w.w * x.w;
      }
      acc += __shfl_xor(acc, 1, 64);
      acc += __shfl_xor(acc, 2, 64);
      if (c4 == 0) gred[r] = acc + b1[row];
    }
    __syncthreads();
    if (tid < 16) {
      float cc = sigm(gred[tid]) * tanhf(gred[16 + tid]);
      float h = sigm(gred[32 + tid]) * tanhf(cc);
      st_dev(xcb + 256 + s * 16 + tid, h);
    }
    group_barrier(cb, (++phase) * NSL, &dead);
    if (dead) break;

    // ---- stage C: proj slice (relu) ----
    hbuf[tid] = ld_dev(xcb + 256 + tid);
    __syncthreads();
    {
      int row = s * 32 + rp;
      const float* wrow = Wproj + (size_t)row * 256 + c8 * 32;
      float acc = 0.f;
#pragma unroll
      for (int i2 = 0; i2 < 8; ++i2) {
        float4 w = *(const float4*)&wrow[i2 * 4];
        float4 x = *(const float4*)&hbuf[c8 * 32 + i2 * 4];
        acc += w.x * x.x + w.y * x.y + w.z * x.z + w.w * x.w;
      }
      acc += __shfl_xor(acc, 1, 64);
      acc += __shfl_xor(acc, 2, 64);
      acc += __shfl_xor(acc, 4, 64);
      if (c8 == 0) {
        float v = fmaxf(acc + bproj[row], 0.f);
        st_dev(xcb + 512 + row, v);
        pc[(size_t)(b * 256 + t) * 1024 + row] = (f16)v;
      }
    }
    group_barrier(cb, (++phase) * NSL, &dead);
    if (dead) break;

    // ---- stage D: scores, local softmax, partial ctx ----
    for (int i = tid; i < 512; i += 256) projf[i] = ld_dev(xcb + 512 + i);
    __syncthreads();
    {
      int kk = rp;                      // 0..31
      int swz = (kk & 7) << 3;
      float acc = 0.f;
#pragma unroll
      for (int j0 = 0; j0 < 64; j0 += 8) {
        f16x8 v = *(const f16x8*)&ench[kk * 512 + ((c8 * 64 + j0) ^ swz)];
#pragma unroll
        for (int jj = 0; jj < 8; ++jj) acc += (float)v[jj] * projf[c8 * 64 + j0 + jj];
      }
      acc += __shfl_xor(acc, 1, 64);
      acc += __shfl_xor(acc, 2, 64);
      acc += __shfl_xor(acc, 4, 64);
      if (c8 == 0) sc_lds[kk] = acc;
    }
    __syncthreads();
    if (tid < 32) {
      float v = sc_lds[tid];
      float m = v;
      m = fmaxf(m, __shfl_xor(m, 16, 64));
      m = fmaxf(m, __shfl_xor(m, 8, 64));
      m = fmaxf(m, __shfl_xor(m, 4, 64));
      m = fmaxf(m, __shfl_xor(m, 2, 64));
      m = fmaxf(m, __shfl_xor(m, 1, 64));
      float e = __expf(v - m);
      el[tid] = e;
      float Ss = e;
      Ss += __shfl_xor(Ss, 16, 64);
      Ss += __shfl_xor(Ss, 8, 64);
      Ss += __shfl_xor(Ss, 4, 64);
      Ss += __shfl_xor(Ss, 2, 64);
      Ss += __shfl_xor(Ss, 1, 64);
      if (tid == 0) { st_dev(xcb + 1024 + 2 * s, m); st_dev(xcb + 1024 + 2 * s + 1, Ss); }
    }
    __syncthreads();
    for (int d = tid; d < 512; d += 256) {
      float c = 0.f;
#pragma unroll
      for (int kk = 0; kk < 32; ++kk)
        c += el[kk] * (float)ench[kk * 512 + (d ^ ((kk & 7) << 3))];
      st_dev(xcb + 1056 + s * 512 + d, c);
    }
    group_barrier(cb, (++phase) * NSL, &dead);
    if (dead) break;

    // ---- combine: global softmax + full ctx (redundant per block) ----
    if (tid < 16) { mred[tid] = ld_dev(xcb + 1024 + 2 * tid); Sred[tid] = ld_dev(xcb + 1024 + 2 * tid + 1); }
    __syncthreads();
    float mg = mred[0];
#pragma unroll
    for (int q = 1; q < 16; ++q) mg = fmaxf(mg, mred[q]);
    float Sg = 0.f;
#pragma unroll
    for (int q = 0; q < 16; ++q) Sg += __expf(mred[q] - mg) * Sred[q];
    float inv = 1.f / Sg;
    for (int d = tid; d < 512; d += 256) {
      float c = 0.f;
#pragma unroll
      for (int q = 0; q < 16; ++q) c += __expf(mred[q] - mg) * ld_dev(xcb + 1056 + q * 512 + d);
      float cv = c * inv;
      ctx_lds[d] = cv;
      if (s == 0) pc[(size_t)(b * 256 + t) * 1024 + 512 + d] = (f16)cv;
    }
    __syncthreads();
  }
}

// ---- K3: OUT[8192,10000] = PC[8192,1024] @ Wout16^T, fp16 MFMA ----
__global__ __launch_bounds__(256) void k_gemm(
    const f16* __restrict__ A, const f16* __restrict__ Bm, float* __restrict__ C)
{
  __shared__ f16 Ah[128 * 40];
  __shared__ f16 Bh[128 * 40];
  int tid = threadIdx.x;
  int tn = blockIdx.x;
  int tm = blockIdx.y;
  int lane = tid & 63, wave = tid >> 6;
  int wm = wave >> 1, wn = wave & 1;
  f32x4 acc[4][4];
#pragma unroll
  for (int i = 0; i < 4; ++i)
#pragma unroll
    for (int q = 0; q < 4; ++q) acc[i][q] = (f32x4){0.f, 0.f, 0.f, 0.f};

  for (int k0 = 0; k0 < 1024; k0 += 32) {
#pragma unroll
    for (int rd = 0; rd < 2; ++rd) {
      int chunk = tid + rd * 256;
      int row = chunk >> 2, cc = (chunk & 3) * 8;
      *(f16x8*)&Ah[row * 40 + cc] = *(const f16x8*)&A[((size_t)(tm * 128 + row)) * 1024 + k0 + cc];
      *(f16x8*)&Bh[row * 40 + cc] = *(const f16x8*)&Bm[((size_t)(tn * 128 + row)) * 1024 + k0 + cc];
    }
    __syncthreads();
    f16x8 af[4], bf[4];
#pragma unroll
    for (int q = 0; q < 4; ++q) {
      af[q] = *(const f16x8*)&Ah[(wm * 64 + q * 16 + (lane & 15)) * 40 + (lane >> 4) * 8];
      bf[q] = *(const f16x8*)&Bh[(wn * 64 + q * 16 + (lane & 15)) * 40 + (lane >> 4) * 8];
    }
#pragma unroll
    for (int i = 0; i < 4; ++i)
#pragma unroll
      for (int q = 0; q < 4; ++q)
        acc[i][q] = __builtin_amdgcn_mfma_f32_16x16x32_f16(af[i], bf[q], acc[i][q], 0, 0, 0);
    __syncthreads();
  }

  int rbase = (lane >> 4) * 4;
  int nloc = lane & 15;
#pragma unroll
  for (int i = 0; i < 4; ++i)
#pragma unroll
    for (int q = 0; q < 4; ++q)
#pragma unroll
      for (int rr = 0; rr < 4; ++rr) {
        int m = tm * 128 + wm * 64 + i * 16 + rbase + rr;
        int n = tn * 128 + wn * 64 + q * 16 + nloc;
        if (n < 10000) C[(size_t)m * 10000 + n] = acc[i][q][rr];
      }
}

extern "C" void kernel_launch(void* const* d_in, const int* in_sizes, int n_in,
                              void* d_out, int out_size, void* d_ws, size_t ws_size,
                              hipStream_t stream)
{
  const float* enc   = (const float*)d_in[0];
  const int*   dec   = (const int*)d_in[1];
  const float* emb   = (const float*)d_in[2];
  const float* Wih0  = (const float*)d_in[3];
  const float* b0    = (const float*)d_in[4];
  const float* Wih1  = (const float*)d_in[5];
  const float* b1    = (const float*)d_in[6];
  const float* Wproj = (const float*)d_in[7];
  const float* bproj = (const float*)d_in[8];
  const float* Wout  = (const float*)d_in[9];
  float* out = (float*)d_out;
  char* ws = (char*)d_ws;

  hipMemsetAsync(ws, 0, 4096, stream);
  k_embed_gates<<<1024, 256, 0, stream>>>(dec, emb, Wih0, b0, (float*)(ws + GE_OFF));
  k_wout_f16<<<(NPAD * 1024) / 4096, 256, 0, stream>>>(Wout, (f16*)(ws + WO_OFF));
  k_seq<<<512, 256, 0, stream>>>(enc, Wih0, Wih1, b1, Wproj, bproj,
                                 (float*)(ws + GE_OFF), (float*)(ws + XC_OFF),
                                 (int*)(ws + CNT_OFF), (f16*)(ws + PC_OFF));
  dim3 g3(79, 64);
  k_gemm<<<g3, 256, 0, stream>>>((const f16*)(ws + PC_OFF), (const f16*)(ws + WO_OFF), out);
}

// Round 2
// 11131.753 us; speedup vs baseline: 3.4627x; 3.4627x over previous
//
#include <hip/hip_runtime.h>
#include <hip/hip_fp16.h>

#define TT 256
#define NB 32
#define KENC 512
#define VV 10000
#define DMM 512
#define NSL 16          // slices (blocks) per batch element
#define KROWS 32        // enc k-rows per slice

typedef _Float16 f16;
typedef _Float16 f16x8 __attribute__((ext_vector_type(8)));
typedef float f32x4 __attribute__((ext_vector_type(4)));

// ---- ws layout (bytes) ----
#define GE_OFF 4096ull
#define GE_BYTES (8192ull*1024ull*4ull)
#define XC_OFF (GE_OFF + GE_BYTES)
#define XC_STRIDE 10240ull   // floats per b (40KB apart -> counters isolated)
#define XC_BYTES (32ull*XC_STRIDE*4ull)
#define PC_OFF (XC_OFF + XC_BYTES)
#define PC_BYTES (8192ull*1024ull*2ull)
#define WO_OFF (PC_OFF + PC_BYTES)
#define NPAD 10112
// counter for b lives at float slot 10000 of its xc stride (40KB separation)
#define CNT_SLOT 10000

__device__ __forceinline__ void st_dev(float* p, float v) {
  __hip_atomic_store(p, v, __ATOMIC_RELAXED, __HIP_MEMORY_SCOPE_AGENT);
}
__device__ __forceinline__ float ld_dev(const float* p) {
  return __hip_atomic_load(p, __ATOMIC_RELAXED, __HIP_MEMORY_SCOPE_AGENT);
}
__device__ __forceinline__ float sigm(float x) { return 1.f / (1.f + __expf(-x)); }

// arrival: release add (orders this block's prior agent stores at the coherent
// point). polling: RELAXED loads only — no per-poll cache invalidates. Readers
// use agent-scope atomic loads which fetch from the coherent point anyway.
__device__ __forceinline__ void group_barrier(int* cb, int target, int* dead_lds) {
  __syncthreads();
  if (threadIdx.x == 0) {
    __hip_atomic_fetch_add(cb, 1, __ATOMIC_RELEASE, __HIP_MEMORY_SCOPE_AGENT);
    int it = 0;
    while (__hip_atomic_load(cb, __ATOMIC_RELAXED, __HIP_MEMORY_SCOPE_AGENT) < target) {
      __builtin_amdgcn_s_sleep(1);
      if (++it > (1 << 17)) { *dead_lds = 1; break; }
    }
  }
  __syncthreads();
}

// ---- K1: tokens -> embedding -> g_e = e @ W_e^T + b0 (all 1024 gate rows) ----
__global__ __launch_bounds__(256) void k_embed_gates(
    const int* __restrict__ dec, const float* __restrict__ emb,
    const float* __restrict__ Wih0, const float* __restrict__ b0,
    float* __restrict__ ge)
{
  __shared__ float e_lds[8][64];
  int tid = threadIdx.x;
  int tb0 = blockIdx.x * 8;
  for (int j = tid; j < 8 * 64; j += 256) {
    int q = j >> 6, d = j & 63;
    int tb = tb0 + q;
    int t = tb >> 5, b = tb & 31;
    int tok;
    if (t == 0) tok = 1;                        // SOS
    else { tok = dec[b * 256 + (t - 1)]; if (tok == 2) tok = 0; }  // EOS->PAD
    e_lds[q][d] = emb[(size_t)tok * 64 + d];
  }
  __syncthreads();
  for (int rr = 0; rr < 4; ++rr) {
    int row = tid + rr * 256;
    float bv = b0[row];
    float acc[8];
#pragma unroll
    for (int q = 0; q < 8; ++q) acc[q] = bv;
    const float* wr = Wih0 + (size_t)row * 576;
#pragma unroll 4
    for (int d4 = 0; d4 < 16; ++d4) {
      float4 w = *(const float4*)&wr[d4 * 4];
#pragma unroll
      for (int q = 0; q < 8; ++q) {
        acc[q] += w.x * e_lds[q][d4 * 4 + 0];
        acc[q] += w.y * e_lds[q][d4 * 4 + 1];
        acc[q] += w.z * e_lds[q][d4 * 4 + 2];
        acc[q] += w.w * e_lds[q][d4 * 4 + 3];
      }
    }
#pragma unroll
    for (int q = 0; q < 8; ++q) ge[(size_t)(tb0 + q) * 1024 + row] = acc[q];
  }
}

// ---- K1b: W_out fp32 -> fp16, padded to NPAD rows ----
__global__ __launch_bounds__(256) void k_wout_f16(const float* __restrict__ W, f16* __restrict__ wo)
{
  size_t base = (size_t)blockIdx.x * 4096 + (size_t)threadIdx.x * 16;
  for (int i = 0; i < 16; ++i) {
    size_t idx = base + i;
    size_t n = idx >> 10;
    float v = (n < 10000) ? W[idx] : 0.f;
    wo[idx] = (f16)v;
  }
}

// ---- K2: sequential scan. 512 blocks = 32 b-groups x 16 slices. ----
// Wih0(ctx part) and Wih1 slices are register-stationary across all 256 steps.
__global__ __launch_bounds__(256, 2) void k_seq(
    const float* __restrict__ enc, const float* __restrict__ Wih0,
    const float* __restrict__ Wih1, const float* __restrict__ b1,
    const float* __restrict__ Wproj, const float* __restrict__ bproj,
    const float* __restrict__ ge, float* __restrict__ xc,
    f16* __restrict__ pc)
{
  __shared__ f16 ench[KROWS * 512];
  __shared__ float ctx_lds[512];
  __shared__ float hbuf[256];
  __shared__ float projf[512];
  __shared__ float gred[64];
  __shared__ float sc_lds[32];
  __shared__ float el[32];
  __shared__ float mred[16], Sred[16];
  __shared__ int dead;

  int tid = threadIdx.x;
  int j = blockIdx.x;
  int b = (j & 7) * 4 + (j >> 7);     // all 16 slices of b share blockIdx%8 (same XCD)
  int s = (j >> 3) & 15;
  float* xcb = xc + (size_t)b * XC_STRIDE;
  int* cb = (int*)(xcb + CNT_SLOT);

  int r = tid >> 2, c4 = tid & 3;
  int rp = tid >> 3, c8 = tid & 7;

  // ---- register-stationary weight slices ----
  int rowA = 0;
  float4 wA[32];   // Wih0 ctx part: 128 floats
  float4 wB[16];   // Wih1: 64 floats
  if (r < 48) {
    int u = (r & 15) + s * 16;
    rowA = (r < 16) ? u : (r < 32) ? 512 + u : 768 + u;
    const float* wra = Wih0 + (size_t)rowA * 576 + 64 + c4 * 128;
#pragma unroll
    for (int i = 0; i < 32; ++i) wA[i] = ((const float4*)wra)[i];
    const float* wrb = Wih1 + (size_t)rowA * 256 + c4 * 64;
#pragma unroll
    for (int i = 0; i < 16; ++i) wB[i] = ((const float4*)wrb)[i];
  }

  // stationary enc slice -> LDS fp16, xor swizzle on d by (kk&7)<<3
  for (int i = tid; i < KROWS * 512; i += 256) {
    int kk = i >> 9, d = i & 511;
    float v = enc[((size_t)b * 512 + (s * KROWS + kk)) * 512 + d];
    ench[kk * 512 + (d ^ ((kk & 7) << 3))] = (f16)v;
  }
  for (int i = tid; i < 512; i += 256) ctx_lds[i] = 0.f;
  if (tid == 0) dead = 0;
  __syncthreads();

  float gev = 0.f;
  if (r < 48 && c4 == 0) gev = ge[(size_t)b * 1024 + rowA];   // t=0

  int phase = 0;
  for (int t = 0; t < TT; ++t) {
    // ---- stage A: gates = g_e + W_c @ ctx ; h0 slice ----
    if (r < 48) {
      float acc = 0.f;
#pragma unroll
      for (int i2 = 0; i2 < 32; ++i2) {
        float4 x = *(const float4*)&ctx_lds[c4 * 128 + i2 * 4];
        acc += wA[i2].x * x.x + wA[i2].y * x.y + wA[i2].z * x.z + wA[i2].w * x.w;
      }
      acc += __shfl_xor(acc, 1, 64);
      acc += __shfl_xor(acc, 2, 64);
      if (c4 == 0) gred[r] = acc + gev;
    }
    __syncthreads();
    if (tid < 16) {
      float cc = sigm(gred[tid]) * tanhf(gred[16 + tid]);
      float h = sigm(gred[32 + tid]) * tanhf(cc);
      st_dev(xcb + s * 16 + tid, h);
    }
    // prefetch next step's ge value (in flight across stages B-D)
    if (t + 1 < TT && r < 48 && c4 == 0)
      gev = ge[(size_t)((t + 1) * 32 + b) * 1024 + rowA];
    group_barrier(cb, (++phase) * NSL, &dead);
    if (dead) break;

    // ---- stage B: h1 slice ----
    hbuf[tid] = ld_dev(xcb + tid);
    __syncthreads();
    if (r < 48) {
      float acc = 0.f;
#pragma unroll
      for (int i2 = 0; i2 < 16; ++i2) {
        float4 x = *(const float4*)&hbuf[c4 * 64 + i2 * 4];
        acc += wB[i2].x * x.x + wB[i2].y * x.y + wB[i2].z * x.z + wB[i2].w * x.w;
      }
      acc += __shfl_xor(acc, 1, 64);
      acc += __shfl_xor(acc, 2, 64);
      if (c4 == 0) gred[r] = acc + b1[rowA];
    }
    __syncthreads();
    if (tid < 16) {
      float cc = sigm(gred[tid]) * tanhf(gred[16 + tid]);
      float h = sigm(gred[32 + tid]) * tanhf(cc);
      st_dev(xcb + 256 + s * 16 + tid, h);
    }
    group_barrier(cb, (++phase) * NSL, &dead);
    if (dead) break;

    // ---- stage C: proj slice (relu) ----
    hbuf[tid] = ld_dev(xcb + 256 + tid);
    __syncthreads();
    {
      int row = s * 32 + rp;
      const float* wrow = Wproj + (size_t)row * 256 + c8 * 32;
      float acc = 0.f;
#pragma unroll
      for (int i2 = 0; i2 < 8; ++i2) {
        float4 w = *(const float4*)&wrow[i2 * 4];
        float4 x = *(const float4*)&hbuf[c8 * 32 + i2 * 4];
        acc += w.x * x.x + w.y * x.y + w.z * x.z + w.w * x.w;
      }
      acc += __shfl_xor(acc, 1, 64);
      acc += __shfl_xor(acc, 2, 64);
      acc += __shfl_xor(acc, 4, 64);
      if (c8 == 0) {
        float v = fmaxf(acc + bproj[row], 0.f);
        st_dev(xcb + 512 + row, v);
        pc[(size_t)(b * 256 + t) * 1024 + row] = (f16)v;
      }
    }
    group_barrier(cb, (++phase) * NSL, &dead);
    if (dead) break;

    // ---- stage D: scores, local softmax, partial ctx ----
    for (int i = tid; i < 512; i += 256) projf[i] = ld_dev(xcb + 512 + i);
    __syncthreads();
    {
      int kk = rp;                      // 0..31
      int swz = (kk & 7) << 3;
      float acc = 0.f;
#pragma unroll
      for (int j0 = 0; j0 < 8; ++j0) {
        int d = j0 * 64 + c8 * 8;       // lane cluster covers 128B bank space
        f16x8 v = *(const f16x8*)&ench[kk * 512 + (d ^ swz)];
        float4 p0 = *(const float4*)&projf[d];
        float4 p1 = *(const float4*)&projf[d + 4];
        acc += (float)v[0] * p0.x + (float)v[1] * p0.y + (float)v[2] * p0.z + (float)v[3] * p0.w;
        acc += (float)v[4] * p1.x + (float)v[5] * p1.y + (float)v[6] * p1.z + (float)v[7] * p1.w;
      }
      acc += __shfl_xor(acc, 1, 64);
      acc += __shfl_xor(acc, 2, 64);
      acc += __shfl_xor(acc, 4, 64);
      if (c8 == 0) sc_lds[kk] = acc;
    }
    __syncthreads();
    if (tid < 32) {
      float v = sc_lds[tid];
      float m = v;
      m = fmaxf(m, __shfl_xor(m, 16, 64));
      m = fmaxf(m, __shfl_xor(m, 8, 64));
      m = fmaxf(m, __shfl_xor(m, 4, 64));
      m = fmaxf(m, __shfl_xor(m, 2, 64));
      m = fmaxf(m, __shfl_xor(m, 1, 64));
      float e = __expf(v - m);
      el[tid] = e;
      float Ss = e;
      Ss += __shfl_xor(Ss, 16, 64);
      Ss += __shfl_xor(Ss, 8, 64);
      Ss += __shfl_xor(Ss, 4, 64);
      Ss += __shfl_xor(Ss, 2, 64);
      Ss += __shfl_xor(Ss, 1, 64);
      if (tid == 0) { st_dev(xcb + 1024 + 2 * s, m); st_dev(xcb + 1024 + 2 * s + 1, Ss); }
    }
    __syncthreads();
    for (int d = tid; d < 512; d += 256) {
      float c = 0.f;
#pragma unroll
      for (int kk = 0; kk < 32; ++kk)
        c += el[kk] * (float)ench[kk * 512 + (d ^ ((kk & 7) << 3))];
      st_dev(xcb + 1056 + s * 512 + d, c);
    }
    group_barrier(cb, (++phase) * NSL, &dead);
    if (dead) break;

    // ---- combine: global softmax + full ctx (replicated per block, no 5th barrier) ----
    if (tid < 16) { mred[tid] = ld_dev(xcb + 1024 + 2 * tid); Sred[tid] = ld_dev(xcb + 1024 + 2 * tid + 1); }
    __syncthreads();
    float mg = mred[0];
#pragma unroll
    for (int q = 1; q < 16; ++q) mg = fmaxf(mg, mred[q]);
    float Sg = 0.f;
#pragma unroll
    for (int q = 0; q < 16; ++q) Sg += __expf(mred[q] - mg) * Sred[q];
    float inv = 1.f / Sg;
    for (int d = tid; d < 512; d += 256) {
      float c = 0.f;
#pragma unroll
      for (int q = 0; q < 16; ++q) c += __expf(mred[q] - mg) * ld_dev(xcb + 1056 + q * 512 + d);
      float cv = c * inv;
      ctx_lds[d] = cv;
      if (s == 0) pc[(size_t)(b * 256 + t) * 1024 + 512 + d] = (f16)cv;
    }
    __syncthreads();
  }
}

// ---- K3: OUT[8192,10000] = PC[8192,1024] @ Wout16^T, fp16 MFMA ----
__global__ __launch_bounds__(256) void k_gemm(
    const f16* __restrict__ A, const f16* __restrict__ Bm, float* __restrict__ C)
{
  __shared__ f16 Ah[128 * 40];
  __shared__ f16 Bh[128 * 40];
  int tid = threadIdx.x;
  int tn = blockIdx.x;
  int tm = blockIdx.y;
  int lane = tid & 63, wave = tid >> 6;
  int wm = wave >> 1, wn = wave & 1;
  f32x4 acc[4][4];
#pragma unroll
  for (int i = 0; i < 4; ++i)
#pragma unroll
    for (int q = 0; q < 4; ++q) acc[i][q] = (f32x4){0.f, 0.f, 0.f, 0.f};

  for (int k0 = 0; k0 < 1024; k0 += 32) {
#pragma unroll
    for (int rd = 0; rd < 2; ++rd) {
      int chunk = tid + rd * 256;
      int row = chunk >> 2, cc = (chunk & 3) * 8;
      *(f16x8*)&Ah[row * 40 + cc] = *(const f16x8*)&A[((size_t)(tm * 128 + row)) * 1024 + k0 + cc];
      *(f16x8*)&Bh[row * 40 + cc] = *(const f16x8*)&Bm[((size_t)(tn * 128 + row)) * 1024 + k0 + cc];
    }
    __syncthreads();
    f16x8 af[4], bf[4];
#pragma unroll
    for (int q = 0; q < 4; ++q) {
      af[q] = *(const f16x8*)&Ah[(wm * 64 + q * 16 + (lane & 15)) * 40 + (lane >> 4) * 8];
      bf[q] = *(const f16x8*)&Bh[(wn * 64 + q * 16 + (lane & 15)) * 40 + (lane >> 4) * 8];
    }
#pragma unroll
    for (int i = 0; i < 4; ++i)
#pragma unroll
      for (int q = 0; q < 4; ++q)
        acc[i][q] = __builtin_amdgcn_mfma_f32_16x16x32_f16(af[i], bf[q], acc[i][q], 0, 0, 0);
    __syncthreads();
  }

  int rbase = (lane >> 4) * 4;
  int nloc = lane & 15;
#pragma unroll
  for (int i = 0; i < 4; ++i)
#pragma unroll
    for (int q = 0; q < 4; ++q)
#pragma unroll
      for (int rr = 0; rr < 4; ++rr) {
        int m = tm * 128 + wm * 64 + i * 16 + rbase + rr;
        int n = tn * 128 + wn * 64 + q * 16 + nloc;
        if (n < 10000) C[(size_t)m * 10000 + n] = acc[i][q][rr];
      }
}

extern "C" void kernel_launch(void* const* d_in, const int* in_sizes, int n_in,
                              void* d_out, int out_size, void* d_ws, size_t ws_size,
                              hipStream_t stream)
{
  const float* enc   = (const float*)d_in[0];
  const int*   dec   = (const int*)d_in[1];
  const float* emb   = (const float*)d_in[2];
  const float* Wih0  = (const float*)d_in[3];
  const float* b0    = (const float*)d_in[4];
  const float* Wih1  = (const float*)d_in[5];
  const float* b1    = (const float*)d_in[6];
  const float* Wproj = (const float*)d_in[7];
  const float* bproj = (const float*)d_in[8];
  const float* Wout  = (const float*)d_in[9];
  float* out = (float*)d_out;
  char* ws = (char*)d_ws;

  // zero the xc region (contains the per-b barrier counters at CNT_SLOT)
  hipMemsetAsync(ws + XC_OFF, 0, XC_BYTES, stream);
  k_embed_gates<<<1024, 256, 0, stream>>>(dec, emb, Wih0, b0, (float*)(ws + GE_OFF));
  k_wout_f16<<<(NPAD * 1024) / 4096, 256, 0, stream>>>(Wout, (f16*)(ws + WO_OFF));
  k_seq<<<512, 256, 0, stream>>>(enc, Wih0, Wih1, b1, Wproj, bproj,
                                 (float*)(ws + GE_OFF), (float*)(ws + XC_OFF),
                                 (f16*)(ws + PC_OFF));
  dim3 g3(79, 64);
  k_gemm<<<g3, 256, 0, stream>>>((const f16*)(ws + PC_OFF), (const f16*)(ws + WO_OFF), out);
}

// Round 3
// 10940.534 us; speedup vs baseline: 3.5232x; 1.0175x over previous
//
#include <hip/hip_runtime.h>
#include <hip/hip_fp16.h>

#define TT 256
#define NB 32
#define KENC 512
#define VV 10000
#define DMM 512
#define NSL 16          // slices (blocks) per batch element
#define KROWS 32        // enc k-rows per slice

typedef _Float16 f16;
typedef _Float16 f16x8 __attribute__((ext_vector_type(8)));
typedef float f32x4 __attribute__((ext_vector_type(4)));

// ---- ws layout (bytes) ----
#define GE_OFF 4096ull
#define GE_BYTES (8192ull*1024ull*4ull)
#define XC_OFF (GE_OFF + GE_BYTES)
#define XC_STRIDE 10240ull   // floats per b (40KB apart)
#define XC_BYTES (32ull*XC_STRIDE*4ull)
#define PC_OFF (XC_OFF + XC_BYTES)
#define PC_BYTES (8192ull*1024ull*2ull)
#define WO_OFF (PC_OFF + PC_BYTES)
#define NPAD 10112
// 16 per-slice flags per group, 128B-aligned: slot 10016 -> byte 40064 = 313*128
#define FLAG_SLOT 10016

__device__ __forceinline__ void st_dev(float* p, float v) {
  __hip_atomic_store(p, v, __ATOMIC_RELAXED, __HIP_MEMORY_SCOPE_AGENT);
}
__device__ __forceinline__ float ld_dev(const float* p) {
  return __hip_atomic_load(p, __ATOMIC_RELAXED, __HIP_MEMORY_SCOPE_AGENT);
}
__device__ __forceinline__ float sigm(float x) { return 1.f / (1.f + __expf(-x)); }

// store-flag barrier: each block release-stores `phase` to its own flag word;
// wave 0 polls all 16 flags with ONE coalesced lane-parallel load. No RMWs.
__device__ __forceinline__ void flag_barrier(int* flags, int s, int phase,
                                             int* dead_lds, int tid) {
  __syncthreads();   // drains all waves' payload stores (vmcnt 0) before flag
  if (tid == 0)
    __hip_atomic_store(&flags[s], phase, __ATOMIC_RELEASE, __HIP_MEMORY_SCOPE_AGENT);
  if (tid < 64) {
    int it = 0;
    for (;;) {
      int f = phase;
      if (tid < 16)
        f = __hip_atomic_load(&flags[tid], __ATOMIC_RELAXED, __HIP_MEMORY_SCOPE_AGENT);
      if (__ballot(f >= phase) == ~0ull) break;
      __builtin_amdgcn_s_sleep(2);
      if (++it > (1 << 17)) { *dead_lds = 1; break; }
    }
  }
  __syncthreads();
}

// ---- K1: tokens -> embedding -> g_e = e @ W_e^T + b0 (all 1024 gate rows) ----
__global__ __launch_bounds__(256) void k_embed_gates(
    const int* __restrict__ dec, const float* __restrict__ emb,
    const float* __restrict__ Wih0, const float* __restrict__ b0,
    float* __restrict__ ge)
{
  __shared__ float e_lds[8][64];
  int tid = threadIdx.x;
  int tb0 = blockIdx.x * 8;
  for (int j = tid; j < 8 * 64; j += 256) {
    int q = j >> 6, d = j & 63;
    int tb = tb0 + q;
    int t = tb >> 5, b = tb & 31;
    int tok;
    if (t == 0) tok = 1;                        // SOS
    else { tok = dec[b * 256 + (t - 1)]; if (tok == 2) tok = 0; }  // EOS->PAD
    e_lds[q][d] = emb[(size_t)tok * 64 + d];
  }
  __syncthreads();
  for (int rr = 0; rr < 4; ++rr) {
    int row = tid + rr * 256;
    float bv = b0[row];
    float acc[8];
#pragma unroll
    for (int q = 0; q < 8; ++q) acc[q] = bv;
    const float* wr = Wih0 + (size_t)row * 576;
#pragma unroll 4
    for (int d4 = 0; d4 < 16; ++d4) {
      float4 w = *(const float4*)&wr[d4 * 4];
#pragma unroll
      for (int q = 0; q < 8; ++q) {
        acc[q] += w.x * e_lds[q][d4 * 4 + 0];
        acc[q] += w.y * e_lds[q][d4 * 4 + 1];
        acc[q] += w.z * e_lds[q][d4 * 4 + 2];
        acc[q] += w.w * e_lds[q][d4 * 4 + 3];
      }
    }
#pragma unroll
    for (int q = 0; q < 8; ++q) ge[(size_t)(tb0 + q) * 1024 + row] = acc[q];
  }
}

// ---- K1b: W_out fp32 -> fp16, padded to NPAD rows ----
__global__ __launch_bounds__(256) void k_wout_f16(const float* __restrict__ W, f16* __restrict__ wo)
{
  size_t base = (size_t)blockIdx.x * 4096 + (size_t)threadIdx.x * 16;
  for (int i = 0; i < 16; ++i) {
    size_t idx = base + i;
    size_t n = idx >> 10;
    float v = (n < 10000) ? W[idx] : 0.f;
    wo[idx] = (f16)v;
  }
}

// ---- K2: sequential scan. 512 blocks = 32 b-groups x 16 slices. ----
__global__ __launch_bounds__(256, 2) void k_seq(
    const float* __restrict__ enc, const float* __restrict__ Wih0,
    const float* __restrict__ Wih1, const float* __restrict__ b1,
    const float* __restrict__ Wproj, const float* __restrict__ bproj,
    const float* __restrict__ ge, float* __restrict__ xc,
    f16* __restrict__ pc)
{
  __shared__ f16 ench[KROWS * 512];
  __shared__ float ctx_lds[512];
  __shared__ float hbuf[256];
  __shared__ float projf[512];
  __shared__ float gred[64];
  __shared__ float sc_lds[32];
  __shared__ float el[32];
  __shared__ float mred[16], Sred[16];
  __shared__ int dead;

  int tid = threadIdx.x;
  int j = blockIdx.x;
  int b = (j & 7) * 4 + (j >> 7);     // all 16 slices of b share blockIdx%8 (same XCD)
  int s = (j >> 3) & 15;
  float* xcb = xc + (size_t)b * XC_STRIDE;
  int* flags = (int*)(xcb + FLAG_SLOT);

  int r = tid >> 2, c4 = tid & 3;
  int rp = tid >> 3, c8 = tid & 7;

  // ---- register-stationary weight slices ----
  int rowA = 0;
  float4 wA[32];   // Wih0 ctx part: 128 floats
  float4 wB[16];   // Wih1: 64 floats
  if (r < 48) {
    int u = (r & 15) + s * 16;
    rowA = (r < 16) ? u : (r < 32) ? 512 + u : 768 + u;
    const float* wra = Wih0 + (size_t)rowA * 576 + 64 + c4 * 128;
#pragma unroll
    for (int i = 0; i < 32; ++i) wA[i] = ((const float4*)wra)[i];
    const float* wrb = Wih1 + (size_t)rowA * 256 + c4 * 64;
#pragma unroll
    for (int i = 0; i < 16; ++i) wB[i] = ((const float4*)wrb)[i];
  }

  // stationary enc slice -> LDS fp16, xor swizzle on d by (kk&7)<<3
  for (int i = tid; i < KROWS * 512; i += 256) {
    int kk = i >> 9, d = i & 511;
    float v = enc[((size_t)b * 512 + (s * KROWS + kk)) * 512 + d];
    ench[kk * 512 + (d ^ ((kk & 7) << 3))] = (f16)v;
  }
  for (int i = tid; i < 512; i += 256) ctx_lds[i] = 0.f;
  if (tid == 0) dead = 0;
  __syncthreads();

  float gev = 0.f;
  if (r < 48 && c4 == 0) gev = ge[(size_t)b * 1024 + rowA];   // t=0

  int phase = 0;
  for (int t = 0; t < TT; ++t) {
    // ---- stage A: gates = g_e + W_c @ ctx ; h0 slice ----
    if (r < 48) {
      float acc = 0.f;
#pragma unroll
      for (int i2 = 0; i2 < 32; ++i2) {
        float4 x = *(const float4*)&ctx_lds[c4 * 128 + i2 * 4];
        acc += wA[i2].x * x.x + wA[i2].y * x.y + wA[i2].z * x.z + wA[i2].w * x.w;
      }
      acc += __shfl_xor(acc, 1, 64);
      acc += __shfl_xor(acc, 2, 64);
      if (c4 == 0) gred[r] = acc + gev;
    }
    __syncthreads();
    if (tid < 16) {
      float cc = sigm(gred[tid]) * tanhf(gred[16 + tid]);
      float h = sigm(gred[32 + tid]) * tanhf(cc);
      st_dev(xcb + s * 16 + tid, h);
    }
    flag_barrier(flags, s, ++phase, &dead, tid);
    if (dead) break;

    // prefetch next step's ge value (in flight across stages B-D; issued AFTER
    // the barrier so the barrier's vmcnt(0) drain doesn't force it early)
    if (t + 1 < TT && r < 48 && c4 == 0)
      gev = ge[(size_t)((t + 1) * 32 + b) * 1024 + rowA];

    // ---- stage B: h1 slice ----
    hbuf[tid] = ld_dev(xcb + tid);
    __syncthreads();
    if (r < 48) {
      float acc = 0.f;
#pragma unroll
      for (int i2 = 0; i2 < 16; ++i2) {
        float4 x = *(const float4*)&hbuf[c4 * 64 + i2 * 4];
        acc += wB[i2].x * x.x + wB[i2].y * x.y + wB[i2].z * x.z + wB[i2].w * x.w;
      }
      acc += __shfl_xor(acc, 1, 64);
      acc += __shfl_xor(acc, 2, 64);
      if (c4 == 0) gred[r] = acc + b1[rowA];
    }
    __syncthreads();
    if (tid < 16) {
      float cc = sigm(gred[tid]) * tanhf(gred[16 + tid]);
      float h = sigm(gred[32 + tid]) * tanhf(cc);
      st_dev(xcb + 256 + s * 16 + tid, h);
    }
    flag_barrier(flags, s, ++phase, &dead, tid);
    if (dead) break;

    // ---- stage C: proj slice (relu) ----
    hbuf[tid] = ld_dev(xcb + 256 + tid);
    __syncthreads();
    {
      int row = s * 32 + rp;
      const float* wrow = Wproj + (size_t)row * 256 + c8 * 32;
      float acc = 0.f;
#pragma unroll
      for (int i2 = 0; i2 < 8; ++i2) {
        float4 w = *(const float4*)&wrow[i2 * 4];
        float4 x = *(const float4*)&hbuf[c8 * 32 + i2 * 4];
        acc += w.x * x.x + w.y * x.y + w.z * x.z + w.w * x.w;
      }
      acc += __shfl_xor(acc, 1, 64);
      acc += __shfl_xor(acc, 2, 64);
      acc += __shfl_xor(acc, 4, 64);
      if (c8 == 0) {
        float v = fmaxf(acc + bproj[row], 0.f);
        st_dev(xcb + 512 + row, v);
        pc[(size_t)(b * 256 + t) * 1024 + row] = (f16)v;
      }
    }
    flag_barrier(flags, s, ++phase, &dead, tid);
    if (dead) break;

    // ---- stage D: scores, local softmax, partial ctx ----
    for (int i = tid; i < 512; i += 256) projf[i] = ld_dev(xcb + 512 + i);
    __syncthreads();
    {
      int kk = rp;                      // 0..31
      int swz = (kk & 7) << 3;
      float acc = 0.f;
#pragma unroll
      for (int j0 = 0; j0 < 8; ++j0) {
        int d = j0 * 64 + c8 * 8;       // lane cluster covers 128B bank space
        f16x8 v = *(const f16x8*)&ench[kk * 512 + (d ^ swz)];
        float4 p0 = *(const float4*)&projf[d];
        float4 p1 = *(const float4*)&projf[d + 4];
        acc += (float)v[0] * p0.x + (float)v[1] * p0.y + (float)v[2] * p0.z + (float)v[3] * p0.w;
        acc += (float)v[4] * p1.x + (float)v[5] * p1.y + (float)v[6] * p1.z + (float)v[7] * p1.w;
      }
      acc += __shfl_xor(acc, 1, 64);
      acc += __shfl_xor(acc, 2, 64);
      acc += __shfl_xor(acc, 4, 64);
      if (c8 == 0) sc_lds[kk] = acc;
    }
    __syncthreads();
    if (tid < 32) {
      float v = sc_lds[tid];
      float m = v;
      m = fmaxf(m, __shfl_xor(m, 16, 64));
      m = fmaxf(m, __shfl_xor(m, 8, 64));
      m = fmaxf(m, __shfl_xor(m, 4, 64));
      m = fmaxf(m, __shfl_xor(m, 2, 64));
      m = fmaxf(m, __shfl_xor(m, 1, 64));
      float e = __expf(v - m);
      el[tid] = e;
      float Ss = e;
      Ss += __shfl_xor(Ss, 16, 64);
      Ss += __shfl_xor(Ss, 8, 64);
      Ss += __shfl_xor(Ss, 4, 64);
      Ss += __shfl_xor(Ss, 2, 64);
      Ss += __shfl_xor(Ss, 1, 64);
      if (tid == 0) { st_dev(xcb + 1024 + 2 * s, m); st_dev(xcb + 1024 + 2 * s + 1, Ss); }
    }
    __syncthreads();
    for (int d = tid; d < 512; d += 256) {
      float c = 0.f;
#pragma unroll
      for (int kk = 0; kk < 32; ++kk)
        c += el[kk] * (float)ench[kk * 512 + (d ^ ((kk & 7) << 3))];
      st_dev(xcb + 1056 + s * 512 + d, c);
    }
    flag_barrier(flags, s, ++phase, &dead, tid);
    if (dead) break;

    // ---- combine: global softmax + full ctx (replicated per block) ----
    if (tid < 16) { mred[tid] = ld_dev(xcb + 1024 + 2 * tid); Sred[tid] = ld_dev(xcb + 1024 + 2 * tid + 1); }
    __syncthreads();
    float mg = mred[0];
#pragma unroll
    for (int q = 1; q < 16; ++q) mg = fmaxf(mg, mred[q]);
    float Sg = 0.f;
#pragma unroll
    for (int q = 0; q < 16; ++q) Sg += __expf(mred[q] - mg) * Sred[q];
    float inv = 1.f / Sg;
    for (int d = tid; d < 512; d += 256) {
      float c = 0.f;
#pragma unroll
      for (int q = 0; q < 16; ++q) c += __expf(mred[q] - mg) * ld_dev(xcb + 1056 + q * 512 + d);
      float cv = c * inv;
      ctx_lds[d] = cv;
      if (s == 0) pc[(size_t)(b * 256 + t) * 1024 + 512 + d] = (f16)cv;
    }
    __syncthreads();
  }
}

// ---- K3: OUT[8192,10000] = PC[8192,1024] @ Wout16^T, fp16 MFMA ----
__global__ __launch_bounds__(256) void k_gemm(
    const f16* __restrict__ A, const f16* __restrict__ Bm, float* __restrict__ C)
{
  __shared__ f16 Ah[128 * 40];
  __shared__ f16 Bh[128 * 40];
  int tid = threadIdx.x;
  int tn = blockIdx.x;
  int tm = blockIdx.y;
  int lane = tid & 63, wave = tid >> 6;
  int wm = wave >> 1, wn = wave & 1;
  f32x4 acc[4][4];
#pragma unroll
  for (int i = 0; i < 4; ++i)
#pragma unroll
    for (int q = 0; q < 4; ++q) acc[i][q] = (f32x4){0.f, 0.f, 0.f, 0.f};

  for (int k0 = 0; k0 < 1024; k0 += 32) {
#pragma unroll
    for (int rd = 0; rd < 2; ++rd) {
      int chunk = tid + rd * 256;
      int row = chunk >> 2, cc = (chunk & 3) * 8;
      *(f16x8*)&Ah[row * 40 + cc] = *(const f16x8*)&A[((size_t)(tm * 128 + row)) * 1024 + k0 + cc];
      *(f16x8*)&Bh[row * 40 + cc] = *(const f16x8*)&Bm[((size_t)(tn * 128 + row)) * 1024 + k0 + cc];
    }
    __syncthreads();
    f16x8 af[4], bf[4];
#pragma unroll
    for (int q = 0; q < 4; ++q) {
      af[q] = *(const f16x8*)&Ah[(wm * 64 + q * 16 + (lane & 15)) * 40 + (lane >> 4) * 8];
      bf[q] = *(const f16x8*)&Bh[(wn * 64 + q * 16 + (lane & 15)) * 40 + (lane >> 4) * 8];
    }
#pragma unroll
    for (int i = 0; i < 4; ++i)
#pragma unroll
      for (int q = 0; q < 4; ++q)
        acc[i][q] = __builtin_amdgcn_mfma_f32_16x16x32_f16(af[i], bf[q], acc[i][q], 0, 0, 0);
    __syncthreads();
  }

  int rbase = (lane >> 4) * 4;
  int nloc = lane & 15;
#pragma unroll
  for (int i = 0; i < 4; ++i)
#pragma unroll
    for (int q = 0; q < 4; ++q)
#pragma unroll
      for (int rr = 0; rr < 4; ++rr) {
        int m = tm * 128 + wm * 64 + i * 16 + rbase + rr;
        int n = tn * 128 + wn * 64 + q * 16 + nloc;
        if (n < 10000) C[(size_t)m * 10000 + n] = acc[i][q][rr];
      }
}

extern "C" void kernel_launch(void* const* d_in, const int* in_sizes, int n_in,
                              void* d_out, int out_size, void* d_ws, size_t ws_size,
                              hipStream_t stream)
{
  const float* enc   = (const float*)d_in[0];
  const int*   dec   = (const int*)d_in[1];
  const float* emb   = (const float*)d_in[2];
  const float* Wih0  = (const float*)d_in[3];
  const float* b0    = (const float*)d_in[4];
  const float* Wih1  = (const float*)d_in[5];
  const float* b1    = (const float*)d_in[6];
  const float* Wproj = (const float*)d_in[7];
  const float* bproj = (const float*)d_in[8];
  const float* Wout  = (const float*)d_in[9];
  float* out = (float*)d_out;
  char* ws = (char*)d_ws;

  // zero the xc region (contains the per-group flag words at FLAG_SLOT)
  hipMemsetAsync(ws + XC_OFF, 0, XC_BYTES, stream);
  k_embed_gates<<<1024, 256, 0, stream>>>(dec, emb, Wih0, b0, (float*)(ws + GE_OFF));
  k_wout_f16<<<(NPAD * 1024) / 4096, 256, 0, stream>>>(Wout, (f16*)(ws + WO_OFF));
  k_seq<<<512, 256, 0, stream>>>(enc, Wih0, Wih1, b1, Wproj, bproj,
                                 (float*)(ws + GE_OFF), (float*)(ws + XC_OFF),
                                 (f16*)(ws + PC_OFF));
  dim3 g3(79, 64);
  k_gemm<<<g3, 256, 0, stream>>>((const f16*)(ws + PC_OFF), (const f16*)(ws + WO_OFF), out);
}

// Round 5
// 6528.156 us; speedup vs baseline: 5.9046x; 1.6759x over previous
//
#include <hip/hip_runtime.h>
#include <hip/hip_fp16.h>

#define TT 256
#define NB 32
#define NSL 16          // slices (blocks) per batch element
#define KROWS 32        // enc k-rows per slice
#define NPAD 10112

typedef _Float16 f16;
typedef _Float16 f16x2h __attribute__((ext_vector_type(2)));
typedef _Float16 f16x8 __attribute__((ext_vector_type(8)));
typedef float f32x2 __attribute__((ext_vector_type(2)));
typedef float f32x4 __attribute__((ext_vector_type(4)));

// ---- per-b exchange layout (floats, within one parity region) ----
#define H0_OFF 0        // 256: h0 full
#define T1_OFF 256      // 16 tags
#define PP_OFF 272      // 16 x 512 proj partials
#define T2_OFF 8464     // 16 tags
#define MS_OFF 8480     // 16 x (m,S)
#define CP_OFF 8512     // 16 x 512 ctx partials
#define T3_OFF 16704    // 16 tags
#define PAR_STRIDE 16768
#define XC_STRIDE 33792ull   // floats per b (two parities + pad)

// ---- ws layout (bytes) ----
#define GE_OFF 4096ull
#define GE_BYTES (8192ull*1024ull*4ull)
#define XC_OFF (GE_OFF + GE_BYTES)
#define XC_BYTES (32ull*XC_STRIDE*4ull)
#define PC_OFF (XC_OFF + XC_BYTES)
#define PC_BYTES (8192ull*1024ull*2ull)
#define WO_OFF (PC_OFF + PC_BYTES)

__device__ __forceinline__ float sigm(float x) { return 1.f / (1.f + __expf(-x)); }

// ---- raw MALL-coherent (sc0 sc1) access primitives ----
__device__ __forceinline__ void st1w_mall(float* p, float v) {
  asm volatile("global_store_dword %0, %1, off sc0 sc1\n\ts_waitcnt vmcnt(0)"
               :: "v"(p), "v"(v) : "memory");
}
__device__ __forceinline__ void st2w_mall(float* p, f32x2 v) {
  asm volatile("global_store_dwordx2 %0, %1, off sc0 sc1\n\ts_waitcnt vmcnt(0)"
               :: "v"(p), "v"(v) : "memory");
}
__device__ __forceinline__ void st_tag(int* p, int v) {
  asm volatile("global_store_dword %0, %1, off sc0 sc1" :: "v"(p), "v"(v) : "memory");
}
__device__ __forceinline__ int ld_tag(const int* p) {
  int r;
  asm volatile("global_load_dword %0, %1, off sc0 sc1\n\ts_waitcnt vmcnt(0)"
               : "=v"(r) : "v"(p) : "memory");
  return r;
}
__device__ __forceinline__ float ld1_mall(const float* p) {
  float r;
  asm volatile("global_load_dword %0, %1, off sc0 sc1\n\ts_waitcnt vmcnt(0)"
               : "=v"(r) : "v"(p) : "memory");
  return r;
}
__device__ __forceinline__ f32x2 ld2_mall(const float* p) {
  f32x2 r;
  asm volatile("global_load_dwordx2 %0, %1, off sc0 sc1\n\ts_waitcnt vmcnt(0)"
               : "=v"(r) : "v"(p) : "memory");
  return r;
}
// 8 pipelined x2 loads at 512-float stride, one waitcnt
__device__ __forceinline__ void ld8x2_mall(const float* base, f32x2* o) {
  asm volatile(
    "global_load_dwordx2 %0, %8, off sc0 sc1\n\t"
    "global_load_dwordx2 %1, %9, off sc0 sc1\n\t"
    "global_load_dwordx2 %2, %10, off sc0 sc1\n\t"
    "global_load_dwordx2 %3, %11, off sc0 sc1\n\t"
    "global_load_dwordx2 %4, %12, off sc0 sc1\n\t"
    "global_load_dwordx2 %5, %13, off sc0 sc1\n\t"
    "global_load_dwordx2 %6, %14, off sc0 sc1\n\t"
    "global_load_dwordx2 %7, %15, off sc0 sc1\n\t"
    "s_waitcnt vmcnt(0)"
    : "=&v"(o[0]), "=&v"(o[1]), "=&v"(o[2]), "=&v"(o[3]),
      "=&v"(o[4]), "=&v"(o[5]), "=&v"(o[6]), "=&v"(o[7])
    : "v"(base), "v"(base + 512), "v"(base + 1024), "v"(base + 1536),
      "v"(base + 2048), "v"(base + 2560), "v"(base + 3072), "v"(base + 3584)
    : "memory");
}

// poll all 16 slice tags (one lane-parallel load per iter)
__device__ __forceinline__ void poll_tags(const int* tagbase, int target,
                                          int* dead_lds, int tid) {
  if (tid < 64) {
    int it = 0;
    for (;;) {
      int f = target;
      if (tid < 16) f = ld_tag(tagbase + tid);
      if (__ballot(f >= target) == ~0ull) break;
      __builtin_amdgcn_s_sleep(2);
      if (++it > (1 << 17)) { *dead_lds = 1; break; }
    }
  }
  __syncthreads();
}

// ---- K1: tokens -> embedding -> g_e = e @ W_e^T + b0 ----
__global__ __launch_bounds__(256) void k_embed_gates(
    const int* __restrict__ dec, const float* __restrict__ emb,
    const float* __restrict__ Wih0, const float* __restrict__ b0,
    float* __restrict__ ge)
{
  __shared__ float e_lds[8][64];
  int tid = threadIdx.x;
  int tb0 = blockIdx.x * 8;
  for (int j = tid; j < 8 * 64; j += 256) {
    int q = j >> 6, d = j & 63;
    int tb = tb0 + q;
    int t = tb >> 5, b = tb & 31;
    int tok;
    if (t == 0) tok = 1;
    else { tok = dec[b * 256 + (t - 1)]; if (tok == 2) tok = 0; }
    e_lds[q][d] = emb[(size_t)tok * 64 + d];
  }
  __syncthreads();
  for (int rr = 0; rr < 4; ++rr) {
    int row = tid + rr * 256;
    float bv = b0[row];
    float acc[8];
#pragma unroll
    for (int q = 0; q < 8; ++q) acc[q] = bv;
    const float* wr = Wih0 + (size_t)row * 576;
#pragma unroll 4
    for (int d4 = 0; d4 < 16; ++d4) {
      float4 w = *(const float4*)&wr[d4 * 4];
#pragma unroll
      for (int q = 0; q < 8; ++q) {
        acc[q] += w.x * e_lds[q][d4 * 4 + 0];
        acc[q] += w.y * e_lds[q][d4 * 4 + 1];
        acc[q] += w.z * e_lds[q][d4 * 4 + 2];
        acc[q] += w.w * e_lds[q][d4 * 4 + 3];
      }
    }
#pragma unroll
    for (int q = 0; q < 8; ++q) ge[(size_t)(tb0 + q) * 1024 + row] = acc[q];
  }
}

// ---- K1b: W_out fp32 -> fp16, padded ----
__global__ __launch_bounds__(256) void k_wout_f16(const float* __restrict__ W, f16* __restrict__ wo)
{
  size_t base = (size_t)blockIdx.x * 4096 + (size_t)threadIdx.x * 16;
  for (int i = 0; i < 16; ++i) {
    size_t idx = base + i;
    size_t n = idx >> 10;
    float v = (n < 10000) ? W[idx] : 0.f;
    wo[idx] = (f16)v;
  }
}

// ---- K2: sequential scan, 3 exchanges/step ----
__global__ __launch_bounds__(256, 2) void k_seq(
    const float* __restrict__ enc, const float* __restrict__ Wih0,
    const float* __restrict__ Wih1, const float* __restrict__ b1,
    const float* __restrict__ Wproj, const float* __restrict__ bproj,
    const float* __restrict__ ge, float* __restrict__ xc,
    f16* __restrict__ pc)
{
  __shared__ f16 ench[KROWS * 512];
  __shared__ float ctx_lds[512];
  __shared__ float hbuf[256];
  __shared__ float projf[512];
  __shared__ float gred[64];
  __shared__ float h1buf[16];
  __shared__ float sc_lds[32];
  __shared__ float el[32];
  __shared__ float wred[16];
  __shared__ float invS;
  __shared__ int dead;

  int tid = threadIdx.x;
  int j = blockIdx.x;
  int b = (j & 7) * 4 + (j >> 7);
  int s = (j >> 3) & 15;
  float* xcb = xc + (size_t)b * XC_STRIDE;

  int r = tid >> 2, c4 = tid & 3;
  int rp = tid >> 3, c8 = tid & 7;

  // ---- register-stationary weight slices ----
  int rowA = 0;
  float b1v = 0.f;
  float4 wA[32];   // Wih0 ctx part
  float4 wB[16];   // Wih1
  if (r < 48) {
    int u = (r & 15) + s * 16;
    rowA = (r < 16) ? u : (r < 32) ? 512 + u : 768 + u;
    const float* wra = Wih0 + (size_t)rowA * 576 + 64 + c4 * 128;
#pragma unroll
    for (int i = 0; i < 32; ++i) wA[i] = ((const float4*)wra)[i];
    const float* wrb = Wih1 + (size_t)rowA * 256 + c4 * 64;
#pragma unroll
    for (int i = 0; i < 16; ++i) wB[i] = ((const float4*)wrb)[i];
    b1v = b1[rowA];
  }
  // W_proj rows 2tid,2tid+1, cols s*16..s*16+16
  float4 wp0[4], wp1[4];
  {
    const float* w0 = Wproj + (size_t)(2 * tid) * 256 + s * 16;
    const float* w1 = w0 + 256;
#pragma unroll
    for (int i = 0; i < 4; ++i) { wp0[i] = ((const float4*)w0)[i]; wp1[i] = ((const float4*)w1)[i]; }
  }
  float bp0 = bproj[2 * tid], bp1 = bproj[2 * tid + 1];

  // stationary enc slice -> LDS fp16, xor swizzle on d by (kk&7)<<3
  for (int i = tid; i < KROWS * 512; i += 256) {
    int kk = i >> 9, d = i & 511;
    float v = enc[((size_t)b * 512 + (s * KROWS + kk)) * 512 + d];
    ench[kk * 512 + (d ^ ((kk & 7) << 3))] = (f16)v;
  }
  for (int i = tid; i < 512; i += 256) ctx_lds[i] = 0.f;
  if (tid == 0) dead = 0;
  __syncthreads();

  float gev = 0.f;
  if (r < 48 && c4 == 0) gev = ge[(size_t)b * 1024 + rowA];   // t=0

  for (int t = 0; t < TT; ++t) {
    float* P = xcb + (t & 1) * PAR_STRIDE;
    int tag = t + 1;

    // ---- stage A: gates = g_e + W_c @ ctx ; h0 slice ----
    if (r < 48) {
      float acc = 0.f;
#pragma unroll
      for (int i2 = 0; i2 < 32; ++i2) {
        float4 x = *(const float4*)&ctx_lds[c4 * 128 + i2 * 4];
        acc += wA[i2].x * x.x + wA[i2].y * x.y + wA[i2].z * x.z + wA[i2].w * x.w;
      }
      acc += __shfl_xor(acc, 1, 64);
      acc += __shfl_xor(acc, 2, 64);
      if (c4 == 0) gred[r] = acc + gev;
    }
    __syncthreads();
    if (tid < 16) {
      float cc = sigm(gred[tid]) * tanhf(gred[16 + tid]);
      float h = sigm(gred[32 + tid]) * tanhf(cc);
      st1w_mall(P + H0_OFF + s * 16 + tid, h);
    }
    if (tid == 0) st_tag((int*)(P + T1_OFF) + s, tag);
    poll_tags((const int*)(P + T1_OFF), tag, &dead, tid);
    if (dead) break;

    // prefetch next ge (independent; overlaps rest of step)
    if (t + 1 < TT && r < 48 && c4 == 0)
      gev = ge[(size_t)((t + 1) * 32 + b) * 1024 + rowA];

    // ---- stage B: gather h0, compute own h1[16] (no exchange) ----
    hbuf[tid] = ld1_mall(P + H0_OFF + tid);
    __syncthreads();
    if (r < 48) {
      float acc = 0.f;
#pragma unroll
      for (int i2 = 0; i2 < 16; ++i2) {
        float4 x = *(const float4*)&hbuf[c4 * 64 + i2 * 4];
        acc += wB[i2].x * x.x + wB[i2].y * x.y + wB[i2].z * x.z + wB[i2].w * x.w;
      }
      acc += __shfl_xor(acc, 1, 64);
      acc += __shfl_xor(acc, 2, 64);
      if (c4 == 0) gred[r] = acc + b1v;
    }
    __syncthreads();
    if (tid < 16) {
      float cc = sigm(gred[tid]) * tanhf(gred[16 + tid]);
      h1buf[tid] = sigm(gred[32 + tid]) * tanhf(cc);
    }
    __syncthreads();

    // ---- stage B2: partial proj (rows 2tid,2tid+1 x own 16 h1 cols) ----
    {
      float4 h0v = ((const float4*)h1buf)[0], h1v = ((const float4*)h1buf)[1];
      float4 h2v = ((const float4*)h1buf)[2], h3v = ((const float4*)h1buf)[3];
      float v0 = wp0[0].x*h0v.x + wp0[0].y*h0v.y + wp0[0].z*h0v.z + wp0[0].w*h0v.w
               + wp0[1].x*h1v.x + wp0[1].y*h1v.y + wp0[1].z*h1v.z + wp0[1].w*h1v.w
               + wp0[2].x*h2v.x + wp0[2].y*h2v.y + wp0[2].z*h2v.z + wp0[2].w*h2v.w
               + wp0[3].x*h3v.x + wp0[3].y*h3v.y + wp0[3].z*h3v.z + wp0[3].w*h3v.w;
      float v1 = wp1[0].x*h0v.x + wp1[0].y*h0v.y + wp1[0].z*h0v.z + wp1[0].w*h0v.w
               + wp1[1].x*h1v.x + wp1[1].y*h1v.y + wp1[1].z*h1v.z + wp1[1].w*h1v.w
               + wp1[2].x*h2v.x + wp1[2].y*h2v.y + wp1[2].z*h2v.z + wp1[2].w*h2v.w
               + wp1[3].x*h3v.x + wp1[3].y*h3v.y + wp1[3].z*h3v.z + wp1[3].w*h3v.w;
      st2w_mall(P + PP_OFF + s * 512 + 2 * tid, (f32x2){v0, v1});
    }
    __syncthreads();
    if (tid == 0) st_tag((int*)(P + T2_OFF) + s, tag);
    poll_tags((const int*)(P + T2_OFF), tag, &dead, tid);
    if (dead) break;

    // ---- stage C: sum 16 partials -> full proj (bias+relu) -> LDS ----
    {
      f32x2 o[16];
      const float* base = P + PP_OFF + 2 * tid;
      ld8x2_mall(base, o);
      ld8x2_mall(base + 8 * 512, o + 8);
      float v0 = bp0, v1 = bp1;
#pragma unroll
      for (int q = 0; q < 16; ++q) { v0 += o[q].x; v1 += o[q].y; }
      v0 = fmaxf(v0, 0.f); v1 = fmaxf(v1, 0.f);
      projf[2 * tid] = v0; projf[2 * tid + 1] = v1;
      if (s == 0) {
        f16x2h pu;
        pu[0] = (f16)v0; pu[1] = (f16)v1;
        *(f16x2h*)&pc[(size_t)(b * 256 + t) * 1024 + 2 * tid] = pu;
      }
    }
    __syncthreads();

    // ---- stage D: scores, local softmax, partial ctx ----
    {
      int kk = rp;
      int swz = (kk & 7) << 3;
      float acc = 0.f;
#pragma unroll
      for (int j0 = 0; j0 < 8; ++j0) {
        int d = j0 * 64 + c8 * 8;
        f16x8 v = *(const f16x8*)&ench[kk * 512 + (d ^ swz)];
        float4 p0 = *(const float4*)&projf[d];
        float4 p1 = *(const float4*)&projf[d + 4];
        acc += (float)v[0]*p0.x + (float)v[1]*p0.y + (float)v[2]*p0.z + (float)v[3]*p0.w;
        acc += (float)v[4]*p1.x + (float)v[5]*p1.y + (float)v[6]*p1.z + (float)v[7]*p1.w;
      }
      acc += __shfl_xor(acc, 1, 64);
      acc += __shfl_xor(acc, 2, 64);
      acc += __shfl_xor(acc, 4, 64);
      if (c8 == 0) sc_lds[kk] = acc;
    }
    __syncthreads();
    if (tid < 32) {
      float v = sc_lds[tid];
      float m = v;
      m = fmaxf(m, __shfl_xor(m, 16, 64));
      m = fmaxf(m, __shfl_xor(m, 8, 64));
      m = fmaxf(m, __shfl_xor(m, 4, 64));
      m = fmaxf(m, __shfl_xor(m, 2, 64));
      m = fmaxf(m, __shfl_xor(m, 1, 64));
      float e = __expf(v - m);
      el[tid] = e;
      float Ss = e;
      Ss += __shfl_xor(Ss, 16, 64);
      Ss += __shfl_xor(Ss, 8, 64);
      Ss += __shfl_xor(Ss, 4, 64);
      Ss += __shfl_xor(Ss, 2, 64);
      Ss += __shfl_xor(Ss, 1, 64);
      if (tid == 0) st2w_mall(P + MS_OFF + 2 * s, (f32x2){m, Ss});
    }
    __syncthreads();
    {
      int d0 = 2 * tid;
      float c0 = 0.f, c1 = 0.f;
#pragma unroll
      for (int kk = 0; kk < 32; ++kk) {
        int sw = (kk & 7) << 3;
        f16x2h pv = *(const f16x2h*)&ench[kk * 512 + (d0 ^ sw)];
        c0 += el[kk] * (float)pv[0];
        c1 += el[kk] * (float)pv[1];
      }
      st2w_mall(P + CP_OFF + s * 512 + d0, (f32x2){c0, c1});
    }
    __syncthreads();
    if (tid == 0) st_tag((int*)(P + T3_OFF) + s, tag);
    poll_tags((const int*)(P + T3_OFF), tag, &dead, tid);
    if (dead) break;

    // ---- combine: global softmax + full ctx ----
    if (tid < 16) {
      f32x2 ms = ld2_mall(P + MS_OFF + 2 * tid);
      float m = ms.x;
      float mg = m;
      mg = fmaxf(mg, __shfl_xor(mg, 1, 64));
      mg = fmaxf(mg, __shfl_xor(mg, 2, 64));
      mg = fmaxf(mg, __shfl_xor(mg, 4, 64));
      mg = fmaxf(mg, __shfl_xor(mg, 8, 64));
      float w = __expf(m - mg);
      wred[tid] = w;
      float Sg = w * ms.y;
      Sg += __shfl_xor(Sg, 1, 64);
      Sg += __shfl_xor(Sg, 2, 64);
      Sg += __shfl_xor(Sg, 4, 64);
      Sg += __shfl_xor(Sg, 8, 64);
      if (tid == 0) invS = 1.f / Sg;
    }
    __syncthreads();
    {
      int d0 = 2 * tid;
      f32x2 o[16];
      const float* base = P + CP_OFF + d0;
      ld8x2_mall(base, o);
      ld8x2_mall(base + 8 * 512, o + 8);
      float v0 = 0.f, v1 = 0.f;
#pragma unroll
      for (int q = 0; q < 16; ++q) { v0 += wred[q] * o[q].x; v1 += wred[q] * o[q].y; }
      float inv = invS;
      v0 *= inv; v1 *= inv;
      ctx_lds[d0] = v0; ctx_lds[d0 + 1] = v1;
      if (s == 0) {
        f16x2h pu;
        pu[0] = (f16)v0; pu[1] = (f16)v1;
        *(f16x2h*)&pc[(size_t)(b * 256 + t) * 1024 + 512 + d0] = pu;
      }
    }
    __syncthreads();
  }
}

// ---- K3: OUT[8192,10000] = PC[8192,1024] @ Wout16^T, fp16 MFMA ----
__global__ __launch_bounds__(256) void k_gemm(
    const f16* __restrict__ A, const f16* __restrict__ Bm, float* __restrict__ C)
{
  __shared__ f16 Ah[128 * 40];
  __shared__ f16 Bh[128 * 40];
  int tid = threadIdx.x;
  int tn = blockIdx.x;
  int tm = blockIdx.y;
  int lane = tid & 63, wave = tid >> 6;
  int wm = wave >> 1, wn = wave & 1;
  f32x4 acc[4][4];
#pragma unroll
  for (int i = 0; i < 4; ++i)
#pragma unroll
    for (int q = 0; q < 4; ++q) acc[i][q] = (f32x4){0.f, 0.f, 0.f, 0.f};

  for (int k0 = 0; k0 < 1024; k0 += 32) {
#pragma unroll
    for (int rd = 0; rd < 2; ++rd) {
      int chunk = tid + rd * 256;
      int row = chunk >> 2, cc = (chunk & 3) * 8;
      *(f16x8*)&Ah[row * 40 + cc] = *(const f16x8*)&A[((size_t)(tm * 128 + row)) * 1024 + k0 + cc];
      *(f16x8*)&Bh[row * 40 + cc] = *(const f16x8*)&Bm[((size_t)(tn * 128 + row)) * 1024 + k0 + cc];
    }
    __syncthreads();
    f16x8 af[4], bf[4];
#pragma unroll
    for (int q = 0; q < 4; ++q) {
      af[q] = *(const f16x8*)&Ah[(wm * 64 + q * 16 + (lane & 15)) * 40 + (lane >> 4) * 8];
      bf[q] = *(const f16x8*)&Bh[(wn * 64 + q * 16 + (lane & 15)) * 40 + (lane >> 4) * 8];
    }
#pragma unroll
    for (int i = 0; i < 4; ++i)
#pragma unroll
      for (int q = 0; q < 4; ++q)
        acc[i][q] = __builtin_amdgcn_mfma_f32_16x16x32_f16(af[i], bf[q], acc[i][q], 0, 0, 0);
    __syncthreads();
  }

  int rbase = (lane >> 4) * 4;
  int nloc = lane & 15;
#pragma unroll
  for (int i = 0; i < 4; ++i)
#pragma unroll
    for (int q = 0; q < 4; ++q)
#pragma unroll
      for (int rr = 0; rr < 4; ++rr) {
        int m = tm * 128 + wm * 64 + i * 16 + rbase + rr;
        int n = tn * 128 + wn * 64 + q * 16 + nloc;
        if (n < 10000) C[(size_t)m * 10000 + n] = acc[i][q][rr];
      }
}

extern "C" void kernel_launch(void* const* d_in, const int* in_sizes, int n_in,
                              void* d_out, int out_size, void* d_ws, size_t ws_size,
                              hipStream_t stream)
{
  const float* enc   = (const float*)d_in[0];
  const int*   dec   = (const int*)d_in[1];
  const float* emb   = (const float*)d_in[2];
  const float* Wih0  = (const float*)d_in[3];
  const float* b0    = (const float*)d_in[4];
  const float* Wih1  = (const float*)d_in[5];
  const float* b1    = (const float*)d_in[6];
  const float* Wproj = (const float*)d_in[7];
  const float* bproj = (const float*)d_in[8];
  const float* Wout  = (const float*)d_in[9];
  float* out = (float*)d_out;
  char* ws = (char*)d_ws;

  // zero the exchange region (tags must start at 0)
  hipMemsetAsync(ws + XC_OFF, 0, XC_BYTES, stream);
  k_embed_gates<<<1024, 256, 0, stream>>>(dec, emb, Wih0, b0, (float*)(ws + GE_OFF));
  k_wout_f16<<<(NPAD * 1024) / 4096, 256, 0, stream>>>(Wout, (f16*)(ws + WO_OFF));
  k_seq<<<512, 256, 0, stream>>>(enc, Wih0, Wih1, b1, Wproj, bproj,
                                 (float*)(ws + GE_OFF), (float*)(ws + XC_OFF),
                                 (f16*)(ws + PC_OFF));
  dim3 g3(79, 64);
  k_gemm<<<g3, 256, 0, stream>>>((const f16*)(ws + PC_OFF), (const f16*)(ws + WO_OFF), out);
}

// Round 7
// 4203.964 us; speedup vs baseline: 9.1689x; 1.5529x over previous
//
#include <hip/hip_runtime.h>
#include <hip/hip_fp16.h>

#define TT 256
#define NSL 8           // slices (blocks) per batch element
#define KR 64           // enc k-rows per slice
#define NPAD 10112

typedef _Float16 f16;
typedef _Float16 f16x8 __attribute__((ext_vector_type(8)));
typedef float f32x2 __attribute__((ext_vector_type(2)));
typedef float f32x4 __attribute__((ext_vector_type(4)));

// ---- per-b exchange layout (floats, within one parity region) ----
#define H0_OFF 0        // 256: h0 full (8 x 32)
#define T1_OFF 256      // 8 tags (own 128B line)
#define PP_OFF 272      // 8 x 512 proj partials
#define T2_OFF 4368     // 8 tags
#define MS_OFF 4400     // 8 x (m,S) (own line)
#define CP_OFF 4416     // 8 x 512 ctx partials
#define T3_OFF 8512     // 8 tags
#define PAR_STRIDE 8576
#define XC_STRIDE 17408ull

// ---- ws layout (bytes) ----
#define GE_OFF 4096ull
#define GE_BYTES (8192ull*1024ull*4ull)
#define XC_OFF (GE_OFF + GE_BYTES)
#define XC_BYTES (32ull*XC_STRIDE*4ull)
#define PC_OFF (XC_OFF + XC_BYTES)
#define PC_BYTES (8192ull*1024ull*2ull)
#define WO_OFF (PC_OFF + PC_BYTES)

__device__ __forceinline__ float sigm(float x) { return 1.f / (1.f + __expf(-x)); }

// ---- raw MALL-coherent (sc0 sc1) primitives — round-5-proven forms ----
__device__ __forceinline__ void st1w(float* p, float v) {
  asm volatile("global_store_dword %0, %1, off sc0 sc1\n\ts_waitcnt vmcnt(0)"
               :: "v"(p), "v"(v) : "memory");
}
__device__ __forceinline__ void st2w(float* p, f32x2 v) {
  asm volatile("global_store_dwordx2 %0, %1, off sc0 sc1\n\ts_waitcnt vmcnt(0)"
               :: "v"(p), "v"(v) : "memory");
}
__device__ __forceinline__ void st_tag(int* p, int v) {
  asm volatile("global_store_dword %0, %1, off sc0 sc1" :: "v"(p), "v"(v) : "memory");
}
__device__ __forceinline__ int ld_tag(const int* p) {
  int r;
  asm volatile("global_load_dword %0, %1, off sc0 sc1\n\ts_waitcnt vmcnt(0)"
               : "=v"(r) : "v"(p) : "memory");
  return r;
}
__device__ __forceinline__ float ld1(const float* p) {
  float r;
  asm volatile("global_load_dword %0, %1, off sc0 sc1\n\ts_waitcnt vmcnt(0)"
               : "=v"(r) : "v"(p) : "memory");
  return r;
}
// 8 pipelined dword loads at 512-float stride, one waitcnt (VGPR addresses)
__device__ __forceinline__ void ld8w(const float* base, float* o) {
  asm volatile(
    "global_load_dword %0, %8, off sc0 sc1\n\t"
    "global_load_dword %1, %9, off sc0 sc1\n\t"
    "global_load_dword %2, %10, off sc0 sc1\n\t"
    "global_load_dword %3, %11, off sc0 sc1\n\t"
    "global_load_dword %4, %12, off sc0 sc1\n\t"
    "global_load_dword %5, %13, off sc0 sc1\n\t"
    "global_load_dword %6, %14, off sc0 sc1\n\t"
    "global_load_dword %7, %15, off sc0 sc1\n\t"
    "s_waitcnt vmcnt(0)"
    : "=&v"(o[0]), "=&v"(o[1]), "=&v"(o[2]), "=&v"(o[3]),
      "=&v"(o[4]), "=&v"(o[5]), "=&v"(o[6]), "=&v"(o[7])
    : "v"(base), "v"(base + 512), "v"(base + 1024), "v"(base + 1536),
      "v"(base + 2048), "v"(base + 2560), "v"(base + 3072), "v"(base + 3584)
    : "memory");
}
// 8 cp loads + 1 (m,S) pair, one waitcnt
__device__ __forceinline__ void ld_cp_ms(const float* cpb, const float* msp,
                                         float* o, f32x2* ms) {
  asm volatile(
    "global_load_dword %0, %9, off sc0 sc1\n\t"
    "global_load_dword %1, %10, off sc0 sc1\n\t"
    "global_load_dword %2, %11, off sc0 sc1\n\t"
    "global_load_dword %3, %12, off sc0 sc1\n\t"
    "global_load_dword %4, %13, off sc0 sc1\n\t"
    "global_load_dword %5, %14, off sc0 sc1\n\t"
    "global_load_dword %6, %15, off sc0 sc1\n\t"
    "global_load_dword %7, %16, off sc0 sc1\n\t"
    "global_load_dwordx2 %8, %17, off sc0 sc1\n\t"
    "s_waitcnt vmcnt(0)"
    : "=&v"(o[0]), "=&v"(o[1]), "=&v"(o[2]), "=&v"(o[3]),
      "=&v"(o[4]), "=&v"(o[5]), "=&v"(o[6]), "=&v"(o[7]), "=&v"(*ms)
    : "v"(cpb), "v"(cpb + 512), "v"(cpb + 1024), "v"(cpb + 1536),
      "v"(cpb + 2048), "v"(cpb + 2560), "v"(cpb + 3072), "v"(cpb + 3584),
      "v"(msp)
    : "memory");
}

// every wave polls the 8 slice tags independently (lanes 0-7)
__device__ __forceinline__ void poll8(const int* tagbase, int target, int* dead_lds) {
  int lane = threadIdx.x & 63;
  int it = 0;
  for (;;) {
    int f = target;
    if (lane < 8) f = ld_tag(tagbase + lane);
    if (__ballot(f >= target) == ~0ull) break;
    __builtin_amdgcn_s_sleep(1);
    if (++it > (1 << 17)) { *dead_lds = 1; break; }
  }
}

// ---- K1: tokens -> embedding -> g_e = e @ W_e^T + b0 ----
__global__ __launch_bounds__(256) void k_embed_gates(
    const int* __restrict__ dec, const float* __restrict__ emb,
    const float* __restrict__ Wih0, const float* __restrict__ b0,
    float* __restrict__ ge)
{
  __shared__ float e_lds[8][64];
  int tid = threadIdx.x;
  int tb0 = blockIdx.x * 8;
  for (int j = tid; j < 8 * 64; j += 256) {
    int q = j >> 6, d = j & 63;
    int tb = tb0 + q;
    int t = tb >> 5, b = tb & 31;
    int tok;
    if (t == 0) tok = 1;
    else { tok = dec[b * 256 + (t - 1)]; if (tok == 2) tok = 0; }
    e_lds[q][d] = emb[(size_t)tok * 64 + d];
  }
  __syncthreads();
  for (int rr = 0; rr < 4; ++rr) {
    int row = tid + rr * 256;
    float bv = b0[row];
    float acc[8];
#pragma unroll
    for (int q = 0; q < 8; ++q) acc[q] = bv;
    const float* wr = Wih0 + (size_t)row * 576;
#pragma unroll 4
    for (int d4 = 0; d4 < 16; ++d4) {
      float4 w = *(const float4*)&wr[d4 * 4];
#pragma unroll
      for (int q = 0; q < 8; ++q) {
        acc[q] += w.x * e_lds[q][d4 * 4 + 0];
        acc[q] += w.y * e_lds[q][d4 * 4 + 1];
        acc[q] += w.z * e_lds[q][d4 * 4 + 2];
        acc[q] += w.w * e_lds[q][d4 * 4 + 3];
      }
    }
#pragma unroll
    for (int q = 0; q < 8; ++q) ge[(size_t)(tb0 + q) * 1024 + row] = acc[q];
  }
}

// ---- K1b: W_out fp32 -> fp16, padded ----
__global__ __launch_bounds__(256) void k_wout_f16(const float* __restrict__ W, f16* __restrict__ wo)
{
  size_t base = (size_t)blockIdx.x * 4096 + (size_t)threadIdx.x * 16;
  for (int i = 0; i < 16; ++i) {
    size_t idx = base + i;
    size_t n = idx >> 10;
    float v = (n < 10000) ? W[idx] : 0.f;
    wo[idx] = (f16)v;
  }
}

// ---- K2: 8 slices x 512 threads per b; fp16 register weights; 3 exchanges ----
__global__ __launch_bounds__(512, 2) void k_seq(
    const float* __restrict__ enc, const float* __restrict__ Wih0,
    const float* __restrict__ Wih1, const float* __restrict__ b1,
    const float* __restrict__ Wproj, const float* __restrict__ bproj,
    const float* __restrict__ ge, float* __restrict__ xc,
    f16* __restrict__ pc)
{
  __shared__ f16 ench[KR * 512];       // 64KB
  __shared__ float ctx_lds[512];
  __shared__ float hbuf[256];
  __shared__ float projf[512];
  __shared__ float gred[96];
  __shared__ float h1buf[32];
  __shared__ float sc_lds[64];
  __shared__ float el[64];
  __shared__ int dead;

  int tid = threadIdx.x;
  int j = blockIdx.x;
  int b = j & 31;                 // slices of b share blockIdx%8 residue
  int s = j >> 5;
  float* xcb = xc + (size_t)b * XC_STRIDE;

  int rr = tid >> 2, c4 = tid & 3;
  int rp = tid >> 3, c8 = tid & 7;

  // ---- fp16 register-stationary weights (112 VGPR total) ----
  f16x8 wA[16];   // Wih0 ctx part: own gate row, 128 cols
  f16x8 wB[8];    // Wih1: own gate row, 64 cols
  f16x8 wp[4];    // Wproj: own row, 32 cols (slice's h1 dims)
  int rowA = 0; float b1v = 0.f;
  if (rr < 96) {
    int g = rr >> 5, d = rr & 31;
    rowA = (g == 0 ? 0 : g == 1 ? 512 : 768) + s * 32 + d;
    const float* wra = Wih0 + (size_t)rowA * 576 + 64 + c4 * 128;
#pragma unroll
    for (int i = 0; i < 16; ++i) {
      float4 x0 = ((const float4*)wra)[2 * i];
      float4 x1 = ((const float4*)wra)[2 * i + 1];
      f16x8 w;
      w[0]=(f16)x0.x; w[1]=(f16)x0.y; w[2]=(f16)x0.z; w[3]=(f16)x0.w;
      w[4]=(f16)x1.x; w[5]=(f16)x1.y; w[6]=(f16)x1.z; w[7]=(f16)x1.w;
      wA[i] = w;
    }
    const float* wrb = Wih1 + (size_t)rowA * 256 + c4 * 64;
#pragma unroll
    for (int i = 0; i < 8; ++i) {
      float4 x0 = ((const float4*)wrb)[2 * i];
      float4 x1 = ((const float4*)wrb)[2 * i + 1];
      f16x8 w;
      w[0]=(f16)x0.x; w[1]=(f16)x0.y; w[2]=(f16)x0.z; w[3]=(f16)x0.w;
      w[4]=(f16)x1.x; w[5]=(f16)x1.y; w[6]=(f16)x1.z; w[7]=(f16)x1.w;
      wB[i] = w;
    }
    b1v = b1[rowA];
  }
  {
    const float* wpr = Wproj + (size_t)tid * 256 + s * 32;
#pragma unroll
    for (int i = 0; i < 4; ++i) {
      float4 x0 = ((const float4*)wpr)[2 * i];
      float4 x1 = ((const float4*)wpr)[2 * i + 1];
      f16x8 w;
      w[0]=(f16)x0.x; w[1]=(f16)x0.y; w[2]=(f16)x0.z; w[3]=(f16)x0.w;
      w[4]=(f16)x1.x; w[5]=(f16)x1.y; w[6]=(f16)x1.z; w[7]=(f16)x1.w;
      wp[i] = w;
    }
  }
  float bpv = bproj[tid];

  // stationary enc slice -> LDS fp16, xor swizzle on d by (kk&7)<<3
  for (int i = tid; i < KR * 512; i += 512) {
    int kk = i >> 9, d = i & 511;
    float v = enc[((size_t)b * 512 + s * KR + kk) * 512 + d];
    ench[kk * 512 + (d ^ ((kk & 7) << 3))] = (f16)v;
  }
  ctx_lds[tid] = 0.f;
  if (tid == 0) dead = 0;
  __syncthreads();

  float gev = 0.f;
  if (rr < 96 && c4 == 0) gev = ge[(size_t)b * 1024 + rowA];   // t=0

  for (int t = 0; t < TT; ++t) {
    float* P = xcb + (t & 1) * PAR_STRIDE;
    int tag = t + 1;

    // ---- stage A: own L0 gate rows = g_e + W_c @ ctx -> own h0[32] ----
    if (rr < 96) {
      float acc = 0.f;
#pragma unroll
      for (int i = 0; i < 16; ++i) {
        f16x8 w = wA[i];
        const float* xx = &ctx_lds[c4 * 128 + i * 8];
        acc += (float)w[0]*xx[0] + (float)w[1]*xx[1] + (float)w[2]*xx[2] + (float)w[3]*xx[3]
             + (float)w[4]*xx[4] + (float)w[5]*xx[5] + (float)w[6]*xx[6] + (float)w[7]*xx[7];
      }
      acc += __shfl_xor(acc, 1, 64);
      acc += __shfl_xor(acc, 2, 64);
      if (c4 == 0) gred[rr] = acc + gev;
    }
    __syncthreads();
    if (tid < 32) {
      float cc = sigm(gred[tid]) * tanhf(gred[32 + tid]);
      float h = sigm(gred[64 + tid]) * tanhf(cc);
      st1w(P + H0_OFF + s * 32 + tid, h);
    }
    if (tid == 0) st_tag((int*)(P + T1_OFF) + s, tag);   // same wave, after waitcnt
    poll8((const int*)(P + T1_OFF), tag, &dead);

    // prefetch next ge (cached load, overlaps rest of step)
    if (t + 1 < TT && rr < 96 && c4 == 0)
      gev = ge[(size_t)((t + 1) * 32 + b) * 1024 + rowA];

    // ---- stage B: gather h0(256), own L1 gate rows -> own h1[32] ----
    if (tid < 256) hbuf[tid] = ld1(P + H0_OFF + tid);
    __syncthreads();
    if (dead) break;
    if (rr < 96) {
      float acc = 0.f;
#pragma unroll
      for (int i = 0; i < 8; ++i) {
        f16x8 w = wB[i];
        const float* xx = &hbuf[c4 * 64 + i * 8];
        acc += (float)w[0]*xx[0] + (float)w[1]*xx[1] + (float)w[2]*xx[2] + (float)w[3]*xx[3]
             + (float)w[4]*xx[4] + (float)w[5]*xx[5] + (float)w[6]*xx[6] + (float)w[7]*xx[7];
      }
      acc += __shfl_xor(acc, 1, 64);
      acc += __shfl_xor(acc, 2, 64);
      if (c4 == 0) gred[rr] = acc + b1v;
    }
    __syncthreads();
    if (tid < 32) {
      float cc = sigm(gred[tid]) * tanhf(gred[32 + tid]);
      h1buf[tid] = sigm(gred[64 + tid]) * tanhf(cc);
    }
    __syncthreads();

    // ---- stage B2: proj partial = Wproj[row, own 32 h1 dims] @ own h1 ----
    {
      float acc = 0.f;
#pragma unroll
      for (int i = 0; i < 4; ++i) {
        f16x8 w = wp[i];
        const float* hh = &h1buf[i * 8];
        acc += (float)w[0]*hh[0] + (float)w[1]*hh[1] + (float)w[2]*hh[2] + (float)w[3]*hh[3]
             + (float)w[4]*hh[4] + (float)w[5]*hh[5] + (float)w[6]*hh[6] + (float)w[7]*hh[7];
      }
      st1w(P + PP_OFF + s * 512 + tid, acc);
    }
    __syncthreads();
    if (tid == 0) st_tag((int*)(P + T2_OFF) + s, tag);
    poll8((const int*)(P + T2_OFF), tag, &dead);

    // ---- stage C: sum 8 partials -> full proj (bias+relu) -> LDS ----
    {
      float o8[8];
      ld8w(P + PP_OFF + tid, o8);
      float v = bpv + o8[0] + o8[1] + o8[2] + o8[3] + o8[4] + o8[5] + o8[6] + o8[7];
      v = fmaxf(v, 0.f);
      projf[tid] = v;
      if (s == 0) pc[(size_t)(b * 256 + t) * 1024 + tid] = (f16)v;
    }
    __syncthreads();
    if (dead) break;

    // ---- stage D: scores (own 64 k-rows), local softmax, ctx partial ----
    {
      int kk = rp;                       // 0..63
      int swz = (kk & 7) << 3;
      float acc = 0.f;
#pragma unroll
      for (int j0 = 0; j0 < 8; ++j0) {
        int d = j0 * 64 + c8 * 8;
        f16x8 v = *(const f16x8*)&ench[kk * 512 + (d ^ swz)];
        float4 p0 = *(const float4*)&projf[d];
        float4 p1 = *(const float4*)&projf[d + 4];
        acc += (float)v[0]*p0.x + (float)v[1]*p0.y + (float)v[2]*p0.z + (float)v[3]*p0.w;
        acc += (float)v[4]*p1.x + (float)v[5]*p1.y + (float)v[6]*p1.z + (float)v[7]*p1.w;
      }
      acc += __shfl_xor(acc, 1, 64);
      acc += __shfl_xor(acc, 2, 64);
      acc += __shfl_xor(acc, 4, 64);
      if (c8 == 0) sc_lds[kk] = acc;
    }
    __syncthreads();
    if (tid < 64) {
      float v = sc_lds[tid];
      float m = v;
      m = fmaxf(m, __shfl_xor(m, 32, 64));
      m = fmaxf(m, __shfl_xor(m, 16, 64));
      m = fmaxf(m, __shfl_xor(m, 8, 64));
      m = fmaxf(m, __shfl_xor(m, 4, 64));
      m = fmaxf(m, __shfl_xor(m, 2, 64));
      m = fmaxf(m, __shfl_xor(m, 1, 64));
      float e = __expf(v - m);
      el[tid] = e;
      float S = e;
      S += __shfl_xor(S, 32, 64);
      S += __shfl_xor(S, 16, 64);
      S += __shfl_xor(S, 8, 64);
      S += __shfl_xor(S, 4, 64);
      S += __shfl_xor(S, 2, 64);
      S += __shfl_xor(S, 1, 64);
      if (tid == 0) st2w(P + MS_OFF + 2 * s, (f32x2){m, S});
    }
    __syncthreads();
    {
      float c = 0.f;
#pragma unroll 8
      for (int kk = 0; kk < 64; ++kk)
        c += el[kk] * (float)ench[kk * 512 + (tid ^ ((kk & 7) << 3))];
      st1w(P + CP_OFF + s * 512 + tid, c);
    }
    __syncthreads();
    if (tid == 0) st_tag((int*)(P + T3_OFF) + s, tag);
    poll8((const int*)(P + T3_OFF), tag, &dead);

    // ---- combine: one 9-load batch (8 cp + own (m,S)); shfl softmax-combine ----
    {
      float o8[8]; f32x2 ms;
      ld_cp_ms(P + CP_OFF + tid, P + MS_OFF + 2 * (tid & 7), o8, &ms);
      float m = ms[0], S = ms[1];
      float mg = m;
      mg = fmaxf(mg, __shfl_xor(mg, 1, 8));
      mg = fmaxf(mg, __shfl_xor(mg, 2, 8));
      mg = fmaxf(mg, __shfl_xor(mg, 4, 8));
      float w = __expf(m - mg);
      float Sg = w * S;
      Sg += __shfl_xor(Sg, 1, 8);
      Sg += __shfl_xor(Sg, 2, 8);
      Sg += __shfl_xor(Sg, 4, 8);
      float inv = 1.f / Sg;
      float v = 0.f;
#pragma unroll
      for (int q = 0; q < 8; ++q) v += __shfl(w, q, 8) * o8[q];
      v *= inv;
      ctx_lds[tid] = v;
      if (s == 0) pc[(size_t)(b * 256 + t) * 1024 + 512 + tid] = (f16)v;
    }
    __syncthreads();
    if (dead) break;
  }
}

// ---- K3: OUT[8192,10000] = PC[8192,1024] @ Wout16^T, fp16 MFMA ----
__global__ __launch_bounds__(256) void k_gemm(
    const f16* __restrict__ A, const f16* __restrict__ Bm, float* __restrict__ C)
{
  __shared__ f16 Ah[128 * 40];
  __shared__ f16 Bh[128 * 40];
  int tid = threadIdx.x;
  int tn = blockIdx.x;
  int tm = blockIdx.y;
  int lane = tid & 63, wave = tid >> 6;
  int wm = wave >> 1, wn = wave & 1;
  f32x4 acc[4][4];
#pragma unroll
  for (int i = 0; i < 4; ++i)
#pragma unroll
    for (int q = 0; q < 4; ++q) acc[i][q] = (f32x4){0.f, 0.f, 0.f, 0.f};

  for (int k0 = 0; k0 < 1024; k0 += 32) {
#pragma unroll
    for (int rd = 0; rd < 2; ++rd) {
      int chunk = tid + rd * 256;
      int row = chunk >> 2, cc = (chunk & 3) * 8;
      *(f16x8*)&Ah[row * 40 + cc] = *(const f16x8*)&A[((size_t)(tm * 128 + row)) * 1024 + k0 + cc];
      *(f16x8*)&Bh[row * 40 + cc] = *(const f16x8*)&Bm[((size_t)(tn * 128 + row)) * 1024 + k0 + cc];
    }
    __syncthreads();
    f16x8 af[4], bf[4];
#pragma unroll
    for (int q = 0; q < 4; ++q) {
      af[q] = *(const f16x8*)&Ah[(wm * 64 + q * 16 + (lane & 15)) * 40 + (lane >> 4) * 8];
      bf[q] = *(const f16x8*)&Bh[(wn * 64 + q * 16 + (lane & 15)) * 40 + (lane >> 4) * 8];
    }
#pragma unroll
    for (int i = 0; i < 4; ++i)
#pragma unroll
      for (int q = 0; q < 4; ++q)
        acc[i][q] = __builtin_amdgcn_mfma_f32_16x16x32_f16(af[i], bf[q], acc[i][q], 0, 0, 0);
    __syncthreads();
  }

  int rbase = (lane >> 4) * 4;
  int nloc = lane & 15;
#pragma unroll
  for (int i = 0; i < 4; ++i)
#pragma unroll
    for (int q = 0; q < 4; ++q)
#pragma unroll
      for (int rr = 0; rr < 4; ++rr) {
        int m = tm * 128 + wm * 64 + i * 16 + rbase + rr;
        int n = tn * 128 + wn * 64 + q * 16 + nloc;
        if (n < 10000) C[(size_t)m * 10000 + n] = acc[i][q][rr];
      }
}

extern "C" void kernel_launch(void* const* d_in, const int* in_sizes, int n_in,
                              void* d_out, int out_size, void* d_ws, size_t ws_size,
                              hipStream_t stream)
{
  const float* enc   = (const float*)d_in[0];
  const int*   dec   = (const int*)d_in[1];
  const float* emb   = (const float*)d_in[2];
  const float* Wih0  = (const float*)d_in[3];
  const float* b0    = (const float*)d_in[4];
  const float* Wih1  = (const float*)d_in[5];
  const float* b1    = (const float*)d_in[6];
  const float* Wproj = (const float*)d_in[7];
  const float* bproj = (const float*)d_in[8];
  const float* Wout  = (const float*)d_in[9];
  float* out = (float*)d_out;
  char* ws = (char*)d_ws;

  // zero the exchange region (tags must start at 0)
  hipMemsetAsync(ws + XC_OFF, 0, XC_BYTES, stream);
  k_embed_gates<<<1024, 256, 0, stream>>>(dec, emb, Wih0, b0, (float*)(ws + GE_OFF));
  k_wout_f16<<<(NPAD * 1024) / 4096, 256, 0, stream>>>(Wout, (f16*)(ws + WO_OFF));
  k_seq<<<256, 512, 0, stream>>>(enc, Wih0, Wih1, b1, Wproj, bproj,
                                 (float*)(ws + GE_OFF), (float*)(ws + XC_OFF),
                                 (f16*)(ws + PC_OFF));
  dim3 g3(79, 64);
  k_gemm<<<g3, 256, 0, stream>>>((const f16*)(ws + PC_OFF), (const f16*)(ws + WO_OFF), out);
}